// Round 9
// baseline (588.373 us; speedup 1.0000x reference)
//
#include <hip/hip_runtime.h>
#include <hip/hip_bf16.h>

#define N_NODES  50000
#define N_EDGES  800000
#define N_GRAPHS 512
#define ECHUNK   400000
#define NTILES   3125   // N_NODES / 16

typedef short bf16x8 __attribute__((ext_vector_type(8)));
typedef float f32x4  __attribute__((ext_vector_type(4)));

// ---------------- workspace layout (BYTE offsets, 256-aligned) ----------------
constexpr size_t B_CNT  = 0;                 // N ints (zeroed)
constexpr size_t ZERO_BYTES = 200192;
constexpr size_t B_OFF  = 200192;            // (N+1) ints
constexpr size_t B_CUR  = 400384;            // N ints
constexpr size_t B_BSUM = 600576;            // 256 ints
constexpr size_t B_SSRC = 601600;            // E ints  (src of sorted edge)
constexpr size_t B_SEID = 3801600;           // E ints  (orig edge id of sorted edge)
constexpr size_t B_FR2  = 7001600;           // mlp MFMA frags, 43008 ushorts
constexpr size_t B_AGG2 = 7134720;           // N*192 f; also aliased as agg1 [N][96]
constexpr size_t B_Q    = 45534720;          // 153.6 MB (q1[E][48]u32 | q2[ECHUNK][96]u32)
constexpr size_t B_H1   = 199134720;         // N*64 f
constexpr size_t B_H2   = 211934720;         // N*64 f
constexpr size_t B_FOLD = 224734720;         // folded weights, 43424 floats
constexpr size_t B_FRAG = 224908416;         // bf16 edge-MFMA fragment weights (22528 ushorts)
// fold-region float offsets
constexpr int F_V1H = 0;      // [64][96]   V1[t][n]
constexpr int F_B1F = 6144;   // [96]
constexpr int F_V2H = 6240;   // [64][192]  V2[t][n]
constexpr int F_B2F = 18528;  // [192]
constexpr int F_U1  = 18720;  // [3][64][64]
constexpr int F_UB1 = 31008;  // [64]
constexpr int F_U2  = 31072;  // [3][64][64]
constexpr int F_UB2 = 43360;  // [64]
constexpr int FOLD_TOTAL = 43424;
// edge frag-region ushort offsets
constexpr int FR_W1E1 = 0;      // [4][64][8]   em1_w1^T A-frags (K padded 16->32)
constexpr int FR_W1E2 = 2048;   // [4][64][8]
constexpr int FR_V1   = 4096;   // [6][2][64][8]  V1 B-frags, k-permuted
constexpr int FR_V2   = 10240;  // [12][2][64][8] V2 B-frags, k-permuted
constexpr int FOLD2_TOTAL = 22528;
// mlp frag-region (fr2) ushort offsets
constexpr int FR3_M1W = 0;      // [3][4][64][8]     c1_w1^T A-frags (K=32)
constexpr int FR3_M1U = 6144;   // [3][4][2][64][8]  U1 B-frags, k-permuted
constexpr int FR3_M2W = 18432;  // [3][4][2][64][8]  c2_w1^T A-frags (K=64)
constexpr int FR3_M2U = 30720;  // [3][4][2][64][8]  U2 B-frags, k-permuted
constexpr int FOLD3_TOTAL = 43008;

__device__ inline float bflo(unsigned int u) { return __uint_as_float(u << 16); }
__device__ inline float bfhi(unsigned int u) { return __uint_as_float(u & 0xFFFF0000u); }
__device__ inline unsigned short bf16u(float x) {
    unsigned int ua = __float_as_uint(x);
    return (unsigned short)((ua + 0x7FFFu + ((ua >> 16) & 1u)) >> 16);
}
__device__ inline unsigned int packbf2(float a, float b) {
    unsigned int ua = __float_as_uint(a), ub = __float_as_uint(b);
    return ((ua + 0x7FFFu + ((ua >> 16) & 1u)) >> 16) |
           ((ub + 0x7FFFu + ((ub >> 16) & 1u)) & 0xFFFF0000u);
}

// ---------------- fold: precompute folded weight products (fp32) ----------------
__global__ __launch_bounds__(256) void fold_kernel(
    const float* __restrict__ em1_w2, const float* __restrict__ em1_b2,
    const float* __restrict__ em2_w2, const float* __restrict__ em2_b2,
    const float* __restrict__ c1_lin_w, const float* __restrict__ c1_lin_b,
    const float* __restrict__ c2_lin_w, const float* __restrict__ c2_lin_b,
    const float* __restrict__ c1_w2, const float* __restrict__ c1_b2,
    const float* __restrict__ c2_w2, const float* __restrict__ c2_b2,
    const float* __restrict__ lin1_w, const float* __restrict__ lin1_b,
    const float* __restrict__ lin2_w, const float* __restrict__ lin2_b,
    float* __restrict__ fw)
{
    int idx = blockIdx.x * 256 + threadIdx.x;
    if (idx >= FOLD_TOTAL) return;
    int r = idx;
    if (r < 6144) {
        int k = r / 96, c = r % 96, i = c / 32, j = c % 32;
        float s = 0.f;
        for (int m = 0; m < 64; m++) s = fmaf(em1_w2[k * 64 + m], c1_lin_w[i * 2048 + m * 32 + j], s);
        fw[F_V1H + r] = s; return;
    }
    r -= 6144;
    if (r < 96) {
        int i = r / 32, j = r % 32;
        float s = c1_lin_b[r];
        for (int m = 0; m < 64; m++) s = fmaf(em1_b2[m], c1_lin_w[i * 2048 + m * 32 + j], s);
        fw[F_B1F + r] = s; return;
    }
    r -= 96;
    if (r < 12288) {
        int k = r / 192, c = r % 192, i = c / 64, j = c % 64;
        float s = 0.f;
        for (int m = 0; m < 64; m++) s = fmaf(em2_w2[k * 64 + m], c2_lin_w[i * 4096 + m * 64 + j], s);
        fw[F_V2H + r] = s; return;
    }
    r -= 12288;
    if (r < 192) {
        int i = r / 64, j = r % 64;
        float s = c2_lin_b[r];
        for (int m = 0; m < 64; m++) s = fmaf(em2_b2[m], c2_lin_w[i * 4096 + m * 64 + j], s);
        fw[F_B2F + r] = s; return;
    }
    r -= 192;
    if (r < 12288) {
        int i = r / 4096, k = (r / 64) % 64, j = r % 64;
        float s = 0.f;
        for (int m = 0; m < 64; m++) s = fmaf(c1_w2[i * 4096 + k * 64 + m], lin1_w[(i * 64 + m) * 64 + j], s);
        fw[F_U1 + r] = s; return;
    }
    r -= 12288;
    if (r < 64) {
        float s = lin1_b[r];
        for (int i = 0; i < 3; i++)
            for (int m = 0; m < 64; m++) s = fmaf(c1_b2[i * 64 + m], lin1_w[(i * 64 + m) * 64 + r], s);
        fw[F_UB1 + r] = s; return;
    }
    r -= 64;
    if (r < 12288) {
        int i = r / 4096, k = (r / 64) % 64, j = r % 64;
        float s = 0.f;
        for (int m = 0; m < 64; m++) s = fmaf(c2_w2[i * 4096 + k * 64 + m], lin2_w[(i * 64 + m) * 64 + j], s);
        fw[F_U2 + r] = s; return;
    }
    r -= 12288;
    {
        float s = lin2_b[r];
        for (int i = 0; i < 3; i++)
            for (int m = 0; m < 64; m++) s = fmaf(c2_b2[i * 64 + m], lin2_w[(i * 64 + m) * 64 + r], s);
        fw[F_UB2 + r] = s; return;
    }
}

// ---------------- fold2: edge-MFMA bf16 fragment weights ----------------
__global__ __launch_bounds__(256) void fold2_kernel(
    const float* __restrict__ em1_w1, const float* __restrict__ em2_w1,
    const float* __restrict__ fw, unsigned short* __restrict__ fr)
{
    int idx = blockIdx.x * 256 + threadIdx.x;
    if (idx >= FOLD2_TOTAL) return;
    if (idx < 4096) {
        const float* w = (idx < 2048) ? em1_w1 : em2_w1;
        int r = idx & 2047;
        int tt = r >> 9, lane = (r >> 3) & 63, j = r & 7;
        int q = lane >> 4, k = q * 8 + j, m = tt * 16 + (lane & 15);
        fr[idx] = (k < 16) ? bf16u(w[k * 64 + m]) : (unsigned short)0;
        return;
    }
    if (idx < 10240) {
        int r = idx - 4096;
        int nt = r / 1024, ka = (r >> 9) & 1, lane = (r >> 3) & 63, j = r & 7;
        int q = lane >> 4;
        int t = 32 * ka + 16 * (j >> 2) + 4 * q + (j & 3);
        int n = nt * 16 + (lane & 15);
        fr[idx] = bf16u(fw[F_V1H + t * 96 + n]);
        return;
    }
    {
        int r = idx - 10240;
        int nt = r / 1024, ka = (r >> 9) & 1, lane = (r >> 3) & 63, j = r & 7;
        int q = lane >> 4;
        int t = 32 * ka + 16 * (j >> 2) + 4 * q + (j & 3);
        int n = nt * 16 + (lane & 15);
        fr[idx] = bf16u(fw[F_V2H + t * 192 + n]);
        return;
    }
}

// ---------------- fold3: node-MLP MFMA fragments ----------------
__global__ __launch_bounds__(256) void fold3_kernel(
    const float* __restrict__ c1_w1, const float* __restrict__ c2_w1,
    const float* __restrict__ fw, unsigned short* __restrict__ fr2)
{
    int idx = blockIdx.x * 256 + threadIdx.x;
    if (idx >= FOLD3_TOTAL) return;
    if (idx < 6144) {
        int i = idx / 2048, r = idx % 2048;
        int tt = r >> 9, lane = (r >> 3) & 63, jj = r & 7;
        int k = (lane >> 4) * 8 + jj, m = tt * 16 + (lane & 15);
        fr2[FR3_M1W + idx] = bf16u(c1_w1[i * 2048 + k * 64 + m]);
        return;
    }
    if (idx < 18432) {
        int r = idx - 6144;
        int i = r / 4096, r2 = r % 4096;
        int b = r2 >> 10, ka = (r2 >> 9) & 1, lane = (r2 >> 3) & 63, jj = r2 & 7;
        int t = 32 * ka + 16 * (jj >> 2) + 4 * (lane >> 4) + (jj & 3);
        int n = b * 16 + (lane & 15);
        fr2[FR3_M1U + r] = bf16u(fw[F_U1 + i * 4096 + t * 64 + n]);
        return;
    }
    if (idx < 30720) {
        int r = idx - 18432;
        int i = r / 4096, r2 = r % 4096;
        int tt = r2 >> 10, ka = (r2 >> 9) & 1, lane = (r2 >> 3) & 63, jj = r2 & 7;
        int k = ka * 32 + (lane >> 4) * 8 + jj, m = tt * 16 + (lane & 15);
        fr2[FR3_M2W + r] = bf16u(c2_w1[i * 4096 + k * 64 + m]);
        return;
    }
    {
        int r = idx - 30720;
        int i = r / 4096, r2 = r % 4096;
        int b = r2 >> 10, ka = (r2 >> 9) & 1, lane = (r2 >> 3) & 63, jj = r2 & 7;
        int t = 32 * ka + 16 * (jj >> 2) + 4 * (lane >> 4) + (jj & 3);
        int n = b * 16 + (lane & 15);
        fr2[FR3_M2U + r] = bf16u(fw[F_U2 + i * 4096 + t * 64 + n]);
        return;
    }
}

// ---------------- counting sort: hist -> scan -> scatter ----------------
__global__ __launch_bounds__(256) void hist_kernel(const int* __restrict__ ei, int* __restrict__ cnt) {
    int e = blockIdx.x * 256 + threadIdx.x;
    if (e < N_EDGES) atomicAdd(&cnt[ei[N_EDGES + e]], 1);
}

__global__ __launch_bounds__(256) void scan1_kernel(const int* __restrict__ cnt,
                                                    int* __restrict__ off, int* __restrict__ bsum) {
    __shared__ int sh[256];
    int t = threadIdx.x, i = blockIdx.x * 256 + t;
    int v = (i < N_NODES) ? cnt[i] : 0;
    sh[t] = v; __syncthreads();
    for (int d = 1; d < 256; d <<= 1) {
        int add = (t >= d) ? sh[t - d] : 0;
        __syncthreads();
        sh[t] += add;
        __syncthreads();
    }
    if (i < N_NODES) off[i] = sh[t] - v;
    if (t == 255) bsum[blockIdx.x] = sh[255];
}

__global__ __launch_bounds__(256) void scan2_kernel(int* __restrict__ bsum) {
    __shared__ int sh[256];
    int t = threadIdx.x;
    int v = (t < 196) ? bsum[t] : 0;
    sh[t] = v; __syncthreads();
    for (int d = 1; d < 256; d <<= 1) {
        int add = (t >= d) ? sh[t - d] : 0;
        __syncthreads();
        sh[t] += add;
        __syncthreads();
    }
    bsum[t] = sh[t] - v;
}

__global__ __launch_bounds__(256) void scan3_kernel(int* __restrict__ off, const int* __restrict__ bsum,
                                                    int* __restrict__ cur) {
    int i = blockIdx.x * 256 + threadIdx.x;
    if (i < N_NODES) {
        int o = off[i] + bsum[i >> 8];
        off[i] = o;
        cur[i] = o;
    }
    if (i == 0) off[N_NODES] = N_EDGES;
}

__global__ __launch_bounds__(256) void scatter_kernel(const int* __restrict__ ei, int* __restrict__ cur,
                                                      int* __restrict__ ssrc, int* __restrict__ seid) {
    int e = blockIdx.x * 256 + threadIdx.x;
    if (e >= N_EDGES) return;
    int d = ei[N_EDGES + e];
    int p = atomicAdd(&cur[d], 1);
    ssrc[p] = ei[e];
    seid[p] = e;
}

// ---------------- MFMA edge projection ----------------
template<int NT>
__global__ __launch_bounds__(256, 2) void edge_mfma_kernel(
    const float* __restrict__ edge_attr, const int* __restrict__ seid,
    const unsigned short* __restrict__ w1frag, const float* __restrict__ b1,
    const unsigned short* __restrict__ vfrag,  const float* __restrict__ bias2,
    unsigned int* __restrict__ qout, int tile0, int nTiles)
{
    const int lane = threadIdx.x & 63;
    const int wid  = threadIdx.x >> 6;
    const int col  = lane & 15;
    const int quad = lane >> 4;

    bf16x8 w1f[4];
#pragma unroll
    for (int tt = 0; tt < 4; tt++)
        w1f[tt] = *(const bf16x8*)(w1frag + (tt * 64 + lane) * 8);
    bf16x8 vf[NT][2];
#pragma unroll
    for (int nt = 0; nt < NT; nt++)
#pragma unroll
        for (int ka = 0; ka < 2; ka++)
            vf[nt][ka] = *(const bf16x8*)(vfrag + ((nt * 2 + ka) * 64 + lane) * 8);
    float4 b1v[4];
#pragma unroll
    for (int tt = 0; tt < 4; tt++)
        b1v[tt] = *(const float4*)(b1 + tt * 16 + quad * 4);
    float b2v[NT];
#pragma unroll
    for (int nt = 0; nt < NT; nt++) b2v[nt] = bias2[nt * 16 + col];

    const int gw = blockIdx.x * 4 + wid;
    const int stride = gridDim.x * 4;
    for (int t = gw; t < nTiles; t += stride) {
        const int s = (tile0 + t) * 16 + col;
        const int e = seid[s];
        bf16x8 eaf;
        uint4 eau = make_uint4(0u, 0u, 0u, 0u);
        if (quad < 2) {
            const float4 v0 = *(const float4*)(edge_attr + (size_t)e * 16 + quad * 8);
            const float4 v1 = *(const float4*)(edge_attr + (size_t)e * 16 + quad * 8 + 4);
            eau.x = packbf2(v0.x, v0.y); eau.y = packbf2(v0.z, v0.w);
            eau.z = packbf2(v1.x, v1.y); eau.w = packbf2(v1.z, v1.w);
        }
        eaf = __builtin_bit_cast(bf16x8, eau);

        f32x4 c1[4];
#pragma unroll
        for (int tt = 0; tt < 4; tt++) {
            f32x4 ci = {b1v[tt].x, b1v[tt].y, b1v[tt].z, b1v[tt].w};
            c1[tt] = __builtin_amdgcn_mfma_f32_16x16x32_bf16(w1f[tt], eaf, ci, 0, 0, 0);
        }

        bf16x8 a2[2];
#pragma unroll
        for (int ka = 0; ka < 2; ka++) {
            uint4 au;
            au.x = packbf2(fmaxf(c1[2 * ka][0], 0.f),     fmaxf(c1[2 * ka][1], 0.f));
            au.y = packbf2(fmaxf(c1[2 * ka][2], 0.f),     fmaxf(c1[2 * ka][3], 0.f));
            au.z = packbf2(fmaxf(c1[2 * ka + 1][0], 0.f), fmaxf(c1[2 * ka + 1][1], 0.f));
            au.w = packbf2(fmaxf(c1[2 * ka + 1][2], 0.f), fmaxf(c1[2 * ka + 1][3], 0.f));
            a2[ka] = __builtin_bit_cast(bf16x8, au);
        }

        f32x4 c2[NT];
#pragma unroll
        for (int nt = 0; nt < NT; nt++) {
            f32x4 ci = {b2v[nt], b2v[nt], b2v[nt], b2v[nt]};
            ci = __builtin_amdgcn_mfma_f32_16x16x32_bf16(a2[0], vf[nt][0], ci, 0, 0, 0);
            c2[nt] = __builtin_amdgcn_mfma_f32_16x16x32_bf16(a2[1], vf[nt][1], ci, 0, 0, 0);
        }

        const size_t rowb = (size_t)t * 16 + quad * 4;
#pragma unroll
        for (int b = 0; b < NT / 2; b++) {
#pragma unroll
            for (int r = 0; r < 4; r++) {
                unsigned int u = packbf2(c2[2 * b][r], c2[2 * b + 1][r]);
                qout[(rowb + r) * (size_t)(NT * 8) + b * 16 + col] = u;
            }
        }
    }
}

// ---------------- gather layer 1: 2-edge unrolled; writes agg1[N][96] TRUE col order ----------------
__global__ __launch_bounds__(64) void gather1_kernel(
    const float* __restrict__ x, const int* __restrict__ off, const int* __restrict__ ssrc,
    const unsigned int* __restrict__ q1, float* __restrict__ agg1)
{
    const int n = blockIdx.x, l = threadIdx.x;
    if (l >= 48) return;
    const int s0 = off[n], s1 = off[n + 1];
    const int c = l & 15;
    const int n1 = (l >> 4) * 32 + c, n2 = n1 + 16;
    float a0 = 0.f, a1 = 0.f, b0 = 0.f, b1 = 0.f;
    int s = s0;
    for (; s + 2 <= s1; s += 2) {
        const int srcA = ssrc[s], srcB = ssrc[s + 1];
        const unsigned int uA = q1[(size_t)s * 48 + l];
        const unsigned int uB = q1[(size_t)(s + 1) * 48 + l];
        const float xA0 = x[(size_t)srcA * 32 + c], xA1 = x[(size_t)srcA * 32 + c + 16];
        const float xB0 = x[(size_t)srcB * 32 + c], xB1 = x[(size_t)srcB * 32 + c + 16];
        a0 += fmaxf(xA0 + bflo(uA), 0.f);
        a1 += fmaxf(xA1 + bfhi(uA), 0.f);
        b0 += fmaxf(xB0 + bflo(uB), 0.f);
        b1 += fmaxf(xB1 + bfhi(uB), 0.f);
    }
    if (s < s1) {
        const int src = ssrc[s];
        const unsigned int u = q1[(size_t)s * 48 + l];
        a0 += fmaxf(x[(size_t)src * 32 + c] + bflo(u), 0.f);
        a1 += fmaxf(x[(size_t)src * 32 + c + 16] + bfhi(u), 0.f);
    }
    agg1[(size_t)n * 96 + n1] = a0 + b0;
    agg1[(size_t)n * 96 + n2] = a1 + b1;
}

// ---------------- node MLP layer 1 via MFMA (16 nodes per wave) ----------------
__global__ __launch_bounds__(256) void mlp1_mfma_kernel(
    const float* __restrict__ x, const float* __restrict__ agg1,
    const unsigned short* __restrict__ fr2, const float* __restrict__ c1_b1,
    const float* __restrict__ fw, float* __restrict__ h1)
{
    const int lane = threadIdx.x & 63, wid = threadIdx.x >> 6;
    const int tile = blockIdx.x * 4 + wid;
    if (tile >= NTILES) return;
    const int col = lane & 15, quad = lane >> 4;
    const int node = tile * 16 + col;

    const float4 xa = *(const float4*)(x + (size_t)node * 32 + quad * 8);
    const float4 xb = *(const float4*)(x + (size_t)node * 32 + quad * 8 + 4);

    f32x4 c2[4];
#pragma unroll
    for (int b = 0; b < 4; b++) {
        const float ub = fw[F_UB1 + b * 16 + col];
        c2[b] = {ub, ub, ub, ub};
    }
#pragma unroll
    for (int i = 0; i < 3; i++) {
        const float4 a0 = *(const float4*)(agg1 + (size_t)node * 96 + i * 32 + quad * 8);
        const float4 a1 = *(const float4*)(agg1 + (size_t)node * 96 + i * 32 + quad * 8 + 4);
        uint4 iu;
        iu.x = packbf2(xa.x + a0.x, xa.y + a0.y);
        iu.y = packbf2(xa.z + a0.z, xa.w + a0.w);
        iu.z = packbf2(xb.x + a1.x, xb.y + a1.y);
        iu.w = packbf2(xb.z + a1.z, xb.w + a1.w);
        const bf16x8 inf = __builtin_bit_cast(bf16x8, iu);

        f32x4 c1[4];
#pragma unroll
        for (int tt = 0; tt < 4; tt++) {
            const bf16x8 wf = *(const bf16x8*)(fr2 + FR3_M1W + ((i * 4 + tt) * 64 + lane) * 8);
            const float4 bi = *(const float4*)(c1_b1 + i * 64 + tt * 16 + quad * 4);
            f32x4 ci = {bi.x, bi.y, bi.z, bi.w};
            c1[tt] = __builtin_amdgcn_mfma_f32_16x16x32_bf16(wf, inf, ci, 0, 0, 0);
        }
        bf16x8 a2[2];
#pragma unroll
        for (int ka = 0; ka < 2; ka++) {
            uint4 au;
            au.x = packbf2(fmaxf(c1[2 * ka][0], 0.f),     fmaxf(c1[2 * ka][1], 0.f));
            au.y = packbf2(fmaxf(c1[2 * ka][2], 0.f),     fmaxf(c1[2 * ka][3], 0.f));
            au.z = packbf2(fmaxf(c1[2 * ka + 1][0], 0.f), fmaxf(c1[2 * ka + 1][1], 0.f));
            au.w = packbf2(fmaxf(c1[2 * ka + 1][2], 0.f), fmaxf(c1[2 * ka + 1][3], 0.f));
            a2[ka] = __builtin_bit_cast(bf16x8, au);
        }
#pragma unroll
        for (int b = 0; b < 4; b++)
#pragma unroll
            for (int ka = 0; ka < 2; ka++) {
                const bf16x8 uf = *(const bf16x8*)(fr2 + FR3_M1U + (((i * 4 + b) * 2 + ka) * 64 + lane) * 8);
                c2[b] = __builtin_amdgcn_mfma_f32_16x16x32_bf16(a2[ka], uf, c2[b], 0, 0, 0);
            }
    }
    const int rowb = tile * 16 + quad * 4;
#pragma unroll
    for (int b = 0; b < 4; b++)
#pragma unroll
        for (int r = 0; r < 4; r++)
            h1[(size_t)(rowb + r) * 64 + b * 16 + col] = fmaxf(c2[b][r], 0.f);
}

// ---------------- gather layer 2 (chunked; 2-edge unrolled; chunk0 writes) ----------------
__global__ __launch_bounds__(64) void gather2_kernel(
    const float* __restrict__ h1, const int* __restrict__ off, const int* __restrict__ ssrc,
    const unsigned int* __restrict__ q2, float* __restrict__ agg2, int lo, int hi, int first)
{
    const int n = blockIdx.x, l = threadIdx.x;
    int s0 = off[n], s1 = off[n + 1];
    if (s0 < lo) s0 = lo;
    if (s1 > hi) s1 = hi;
    if (!first && s0 >= s1) return;

    const int k1 = ((l >> 4) & 1) * 32 + (l & 15);
    float sa0 = 0.f, sa1 = 0.f, sb0 = 0.f, sb1 = 0.f;
    float ta0 = 0.f, ta1 = 0.f, tb0 = 0.f, tb1 = 0.f;
    int s = s0;
    for (; s + 2 <= s1; s += 2) {
        const int srcA = ssrc[s], srcB = ssrc[s + 1];
        const float hA0 = h1[(size_t)srcA * 64 + k1];
        const float hA1 = h1[(size_t)srcA * 64 + k1 + 16];
        const float hB0 = h1[(size_t)srcB * 64 + k1];
        const float hB1 = h1[(size_t)srcB * 64 + k1 + 16];
        const unsigned int uA = q2[(size_t)(s - lo) * 96 + l];
        const unsigned int uB = q2[(size_t)(s + 1 - lo) * 96 + l];
        sa0 += fmaxf(hA0 + bflo(uA), 0.f);
        sa1 += fmaxf(hA1 + bfhi(uA), 0.f);
        ta0 += fmaxf(hB0 + bflo(uB), 0.f);
        ta1 += fmaxf(hB1 + bfhi(uB), 0.f);
        if (l < 32) {
            const unsigned int u2A = q2[(size_t)(s - lo) * 96 + 64 + l];
            const unsigned int u2B = q2[(size_t)(s + 1 - lo) * 96 + 64 + l];
            sb0 += fmaxf(hA0 + bflo(u2A), 0.f);
            sb1 += fmaxf(hA1 + bfhi(u2A), 0.f);
            tb0 += fmaxf(hB0 + bflo(u2B), 0.f);
            tb1 += fmaxf(hB1 + bfhi(u2B), 0.f);
        }
    }
    if (s < s1) {
        const int src = ssrc[s];
        const float hv0 = h1[(size_t)src * 64 + k1];
        const float hv1 = h1[(size_t)src * 64 + k1 + 16];
        const unsigned int u = q2[(size_t)(s - lo) * 96 + l];
        sa0 += fmaxf(hv0 + bflo(u), 0.f);
        sa1 += fmaxf(hv1 + bfhi(u), 0.f);
        if (l < 32) {
            const unsigned int u2 = q2[(size_t)(s - lo) * 96 + 64 + l];
            sb0 += fmaxf(hv0 + bflo(u2), 0.f);
            sb1 += fmaxf(hv1 + bfhi(u2), 0.f);
        }
    }
    sa0 += ta0; sa1 += ta1; sb0 += tb0; sb1 += tb1;
    const int C1 = 32 * (l >> 4) + (l & 15);
    const int C2 = 128 + 32 * (l >> 4) + (l & 15);
    float* row = agg2 + (size_t)n * 192;
    if (first) {
        row[C1] = sa0; row[C1 + 16] = sa1;
        if (l < 32) { row[C2] = sb0; row[C2 + 16] = sb1; }
    } else {
        row[C1] += sa0; row[C1 + 16] += sa1;
        if (l < 32) { row[C2] += sb0; row[C2 + 16] += sb1; }
    }
}

// ---------------- node MLP layer 2 via MFMA (16 nodes per wave) ----------------
__global__ __launch_bounds__(256) void mlp2_mfma_kernel(
    const float* __restrict__ h1, const float* __restrict__ agg2,
    const unsigned short* __restrict__ fr2, const float* __restrict__ c2_b1,
    const float* __restrict__ fw, float* __restrict__ h2)
{
    const int lane = threadIdx.x & 63, wid = threadIdx.x >> 6;
    const int tile = blockIdx.x * 4 + wid;
    if (tile >= NTILES) return;
    const int col = lane & 15, quad = lane >> 4;
    const int node = tile * 16 + col;

    float4 hv[4];
#pragma unroll
    for (int p = 0; p < 4; p++)
        hv[p] = *(const float4*)(h1 + (size_t)node * 64 + (p >> 1) * 32 + quad * 8 + (p & 1) * 4);

    f32x4 c2[4];
#pragma unroll
    for (int b = 0; b < 4; b++) {
        const float ub = fw[F_UB2 + b * 16 + col];
        c2[b] = {ub, ub, ub, ub};
    }
#pragma unroll
    for (int i = 0; i < 3; i++) {
        bf16x8 inf[2];
#pragma unroll
        for (int ka = 0; ka < 2; ka++) {
            const float4 a0 = *(const float4*)(agg2 + (size_t)node * 192 + i * 64 + ka * 32 + quad * 8);
            const float4 a1 = *(const float4*)(agg2 + (size_t)node * 192 + i * 64 + ka * 32 + quad * 8 + 4);
            const float4 h0 = hv[ka * 2], h1v = hv[ka * 2 + 1];
            uint4 iu;
            iu.x = packbf2(h0.x + a0.x, h0.y + a0.y);
            iu.y = packbf2(h0.z + a0.z, h0.w + a0.w);
            iu.z = packbf2(h1v.x + a1.x, h1v.y + a1.y);
            iu.w = packbf2(h1v.z + a1.z, h1v.w + a1.w);
            inf[ka] = __builtin_bit_cast(bf16x8, iu);
        }
        f32x4 c1[4];
#pragma unroll
        for (int tt = 0; tt < 4; tt++) {
            const bf16x8 wf0 = *(const bf16x8*)(fr2 + FR3_M2W + (((i * 4 + tt) * 2 + 0) * 64 + lane) * 8);
            const bf16x8 wf1 = *(const bf16x8*)(fr2 + FR3_M2W + (((i * 4 + tt) * 2 + 1) * 64 + lane) * 8);
            const float4 bi = *(const float4*)(c2_b1 + i * 64 + tt * 16 + quad * 4);
            f32x4 ci = {bi.x, bi.y, bi.z, bi.w};
            ci = __builtin_amdgcn_mfma_f32_16x16x32_bf16(wf0, inf[0], ci, 0, 0, 0);
            c1[tt] = __builtin_amdgcn_mfma_f32_16x16x32_bf16(wf1, inf[1], ci, 0, 0, 0);
        }
        bf16x8 a2[2];
#pragma unroll
        for (int ka = 0; ka < 2; ka++) {
            uint4 au;
            au.x = packbf2(fmaxf(c1[2 * ka][0], 0.f),     fmaxf(c1[2 * ka][1], 0.f));
            au.y = packbf2(fmaxf(c1[2 * ka][2], 0.f),     fmaxf(c1[2 * ka][3], 0.f));
            au.z = packbf2(fmaxf(c1[2 * ka + 1][0], 0.f), fmaxf(c1[2 * ka + 1][1], 0.f));
            au.w = packbf2(fmaxf(c1[2 * ka + 1][2], 0.f), fmaxf(c1[2 * ka + 1][3], 0.f));
            a2[ka] = __builtin_bit_cast(bf16x8, au);
        }
#pragma unroll
        for (int b = 0; b < 4; b++)
#pragma unroll
            for (int ka = 0; ka < 2; ka++) {
                const bf16x8 uf = *(const bf16x8*)(fr2 + FR3_M2U + (((i * 4 + b) * 2 + ka) * 64 + lane) * 8);
                c2[b] = __builtin_amdgcn_mfma_f32_16x16x32_bf16(a2[ka], uf, c2[b], 0, 0, 0);
            }
    }
    const int rowb = tile * 16 + quad * 4;
#pragma unroll
    for (int b = 0; b < 4; b++)
#pragma unroll
        for (int r = 0; r < 4; r++)
            h2[(size_t)(rowb + r) * 64 + b * 16 + col] = fmaxf(c2[b][r], 0.f);
}

// ---------------- pooling + head (fused; batch is sorted) ----------------
__global__ __launch_bounds__(256) void pool_kernel(
    const float* __restrict__ h2, const int* __restrict__ batch,
    const float* __restrict__ u, const float* __restrict__ fc_w,
    const float* __restrict__ fc_b, float* __restrict__ out)
{
    __shared__ float red[256];
    const int g = blockIdx.x, t = threadIdx.x;
    int lo = 0, hi = N_NODES;
    while (lo < hi) { int m = (lo + hi) >> 1; if (batch[m] < g) lo = m + 1; else hi = m; }
    int lo2 = lo, hi2 = N_NODES;
    while (lo2 < hi2) { int m = (lo2 + hi2) >> 1; if (batch[m] < g + 1) lo2 = m + 1; else hi2 = m; }

    const int col = t & 63, ch = t >> 6;
    float s = 0.f;
    for (int idx = lo + ch; idx < lo2; idx += 4) s += h2[(size_t)idx * 64 + col];
    red[t] = s;
    __syncthreads();
    if (t < 64) red[t] = red[t] + red[64 + t] + red[128 + t] + red[192 + t];
    __syncthreads();
    if (t == 0) {
        const float inv = 1.f / fmaxf((float)(lo2 - lo), 1.f);
        float sv = fc_b[0];
        for (int j = 0; j < 64; j++) sv = fmaf(red[j] * inv, fc_w[j], sv);
        for (int k = 0; k < 32; k++) sv = fmaf(u[(size_t)g * 32 + k], fc_w[64 + k], sv);
        out[g] = sv;
    }
}

extern "C" void kernel_launch(void* const* d_in, const int* in_sizes, int n_in,
                              void* d_out, int out_size, void* d_ws, size_t ws_size,
                              hipStream_t stream) {
    (void)in_sizes; (void)n_in; (void)out_size; (void)ws_size;
    const float* x        = (const float*)d_in[0];
    const float* edge_attr= (const float*)d_in[1];
    const float* u        = (const float*)d_in[2];
    const float* em1_w1   = (const float*)d_in[3];
    const float* em1_b1   = (const float*)d_in[4];
    const float* em1_w2   = (const float*)d_in[5];
    const float* em1_b2   = (const float*)d_in[6];
    const float* em2_w1   = (const float*)d_in[7];
    const float* em2_b1   = (const float*)d_in[8];
    const float* em2_w2   = (const float*)d_in[9];
    const float* em2_b2   = (const float*)d_in[10];
    const float* c1_lin_w = (const float*)d_in[11];
    const float* c1_lin_b = (const float*)d_in[12];
    const float* c1_w1    = (const float*)d_in[13];
    const float* c1_b1    = (const float*)d_in[14];
    const float* c1_w2    = (const float*)d_in[15];
    const float* c1_b2    = (const float*)d_in[16];
    const float* c2_lin_w = (const float*)d_in[17];
    const float* c2_lin_b = (const float*)d_in[18];
    const float* c2_w1    = (const float*)d_in[19];
    const float* c2_b1    = (const float*)d_in[20];
    const float* c2_w2    = (const float*)d_in[21];
    const float* c2_b2    = (const float*)d_in[22];
    const float* lin1_w   = (const float*)d_in[23];
    const float* lin1_b   = (const float*)d_in[24];
    const float* lin2_w   = (const float*)d_in[25];
    const float* lin2_b   = (const float*)d_in[26];
    const float* fc_w     = (const float*)d_in[27];
    const float* fc_b     = (const float*)d_in[28];
    const int*   ei       = (const int*)d_in[29];
    const int*   batch    = (const int*)d_in[30];

    char* wsb = (char*)d_ws;
    int*   cnt  = (int*)(wsb + B_CNT);
    int*   off  = (int*)(wsb + B_OFF);
    int*   cur  = (int*)(wsb + B_CUR);
    int*   bsum = (int*)(wsb + B_BSUM);
    int*   ssrc = (int*)(wsb + B_SSRC);
    int*   seid = (int*)(wsb + B_SEID);
    float* agg2 = (float*)(wsb + B_AGG2);   // also used as agg1 [N][96]
    unsigned int* q = (unsigned int*)(wsb + B_Q);
    float* h1   = (float*)(wsb + B_H1);
    float* h2   = (float*)(wsb + B_H2);
    float* fw   = (float*)(wsb + B_FOLD);
    unsigned short* fr  = (unsigned short*)(wsb + B_FRAG);
    unsigned short* fr2 = (unsigned short*)(wsb + B_FR2);
    float* out  = (float*)d_out;

    (void)hipMemsetAsync(d_ws, 0, ZERO_BYTES, stream);   // histogram counters only

    fold_kernel<<<(FOLD_TOTAL + 255) / 256, 256, 0, stream>>>(
        em1_w2, em1_b2, em2_w2, em2_b2, c1_lin_w, c1_lin_b, c2_lin_w, c2_lin_b,
        c1_w2, c1_b2, c2_w2, c2_b2, lin1_w, lin1_b, lin2_w, lin2_b, fw);
    fold2_kernel<<<(FOLD2_TOTAL + 255) / 256, 256, 0, stream>>>(em1_w1, em2_w1, fw, fr);
    fold3_kernel<<<(FOLD3_TOTAL + 255) / 256, 256, 0, stream>>>(c1_w1, c2_w1, fw, fr2);

    // counting sort by dst
    hist_kernel<<<N_EDGES / 256, 256, 0, stream>>>(ei, cnt);
    scan1_kernel<<<196, 256, 0, stream>>>(cnt, off, bsum);
    scan2_kernel<<<1, 256, 0, stream>>>(bsum);
    scan3_kernel<<<196, 256, 0, stream>>>(off, bsum, cur);
    scatter_kernel<<<N_EDGES / 256, 256, 0, stream>>>(ei, cur, ssrc, seid);

    // layer 1 (grid raised 512->2048: was grid-limited to 8 waves/CU)
    edge_mfma_kernel<6><<<2048, 256, 0, stream>>>(
        edge_attr, seid, fr + FR_W1E1, em1_b1, fr + FR_V1, fw + F_B1F, q, 0, N_EDGES / 16);
    gather1_kernel<<<N_NODES, 64, 0, stream>>>(x, off, ssrc, q, agg2);
    mlp1_mfma_kernel<<<(NTILES + 3) / 4, 256, 0, stream>>>(x, agg2, fr2, c1_b1, fw, h1);

    // layer 2 (two chunks, q buffer reused; grid raised 512->1024)
    for (int c = 0; c < 2; c++) {
        const int lo = c * ECHUNK, hi = lo + ECHUNK;
        edge_mfma_kernel<12><<<1024, 256, 0, stream>>>(
            edge_attr, seid, fr + FR_W1E2, em2_b1, fr + FR_V2, fw + F_B2F, q,
            lo / 16, ECHUNK / 16);
        gather2_kernel<<<N_NODES, 64, 0, stream>>>(h1, off, ssrc, q, agg2, lo, hi, c == 0 ? 1 : 0);
    }
    mlp2_mfma_kernel<<<(NTILES + 3) / 4, 256, 0, stream>>>(h1, agg2, fr2, c2_b1, fw, h2);

    // pooling + head (fused)
    pool_kernel<<<N_GRAPHS, 256, 0, stream>>>(h2, batch, u, fc_w, fc_b, out);
}

// Round 10
// 503.414 us; speedup vs baseline: 1.1688x; 1.1688x over previous
//
#include <hip/hip_runtime.h>
#include <hip/hip_bf16.h>

#define N_NODES  50000
#define N_EDGES  800000
#define N_GRAPHS 512
#define ECHUNK   400000
#define NTILES   3125   // N_NODES / 16

typedef short bf16x8 __attribute__((ext_vector_type(8)));
typedef float f32x4  __attribute__((ext_vector_type(4)));
typedef float f32x2  __attribute__((ext_vector_type(2)));

// ---------------- workspace layout (BYTE offsets, 256-aligned) ----------------
constexpr size_t B_CNT  = 0;                 // N ints (zeroed)
constexpr size_t ZERO_BYTES = 200192;
constexpr size_t B_OFF  = 200192;            // (N+1) ints
constexpr size_t B_CUR  = 400384;            // N ints
constexpr size_t B_BSUM = 600576;            // 256 ints
constexpr size_t B_SSRC = 601600;            // E ints  (src of sorted edge)
constexpr size_t B_SEID = 3801600;           // E ints  (orig edge id of sorted edge)
constexpr size_t B_FR2  = 7001600;           // mlp MFMA frags, 43008 ushorts
constexpr size_t B_AGG2 = 7134720;           // N*192 f; also aliased as agg1 [N][96]
constexpr size_t B_Q    = 45534720;          // fp8 q: q1[E][48]u16 (76.8MB) | q2[ECHUNK][96]u16
constexpr size_t B_H1   = 199134720;         // N*64 f
constexpr size_t B_H2   = 211934720;         // N*64 f
constexpr size_t B_FOLD = 224734720;         // folded weights, 43424 floats
constexpr size_t B_FRAG = 224908416;         // bf16 edge-MFMA fragment weights (22528 ushorts)
// fold-region float offsets
constexpr int F_V1H = 0;      // [64][96]   V1[t][n]
constexpr int F_B1F = 6144;   // [96]
constexpr int F_V2H = 6240;   // [64][192]  V2[t][n]
constexpr int F_B2F = 18528;  // [192]
constexpr int F_U1  = 18720;  // [3][64][64]
constexpr int F_UB1 = 31008;  // [64]
constexpr int F_U2  = 31072;  // [3][64][64]
constexpr int F_UB2 = 43360;  // [64]
constexpr int FOLD_TOTAL = 43424;
// edge frag-region ushort offsets
constexpr int FR_W1E1 = 0;      // [4][64][8]   em1_w1^T A-frags (K padded 16->32)
constexpr int FR_W1E2 = 2048;   // [4][64][8]
constexpr int FR_V1   = 4096;   // [6][2][64][8]  V1 B-frags, k-permuted
constexpr int FR_V2   = 10240;  // [12][2][64][8] V2 B-frags, k-permuted
constexpr int FOLD2_TOTAL = 22528;
// mlp frag-region (fr2) ushort offsets
constexpr int FR3_M1W = 0;      // [3][4][64][8]     c1_w1^T A-frags (K=32)
constexpr int FR3_M1U = 6144;   // [3][4][2][64][8]  U1 B-frags, k-permuted
constexpr int FR3_M2W = 18432;  // [3][4][2][64][8]  c2_w1^T A-frags (K=64)
constexpr int FR3_M2U = 30720;  // [3][4][2][64][8]  U2 B-frags, k-permuted
constexpr int FOLD3_TOTAL = 43008;

__device__ inline unsigned short bf16u(float x) {
    unsigned int ua = __float_as_uint(x);
    return (unsigned short)((ua + 0x7FFFu + ((ua >> 16) & 1u)) >> 16);
}
__device__ inline unsigned int packbf2(float a, float b) {
    unsigned int ua = __float_as_uint(a), ub = __float_as_uint(b);
    return ((ua + 0x7FFFu + ((ua >> 16) & 1u)) >> 16) |
           ((ub + 0x7FFFu + ((ub >> 16) & 1u)) & 0xFFFF0000u);
}
// fp8 e4m3 pack/unpack (HW cvt; OCP on gfx950). Pair layout: byte0=a, byte1=b.
__device__ inline unsigned short pkfp8(float a, float b) {
    return (unsigned short)__builtin_amdgcn_cvt_pk_fp8_f32(a, b, 0, false);
}
__device__ inline f32x2 unpkfp8(unsigned short us) {
    return __builtin_amdgcn_cvt_pk_f32_fp8((int)us, false);
}

// ---------------- fold: precompute folded weight products (fp32) ----------------
__global__ __launch_bounds__(256) void fold_kernel(
    const float* __restrict__ em1_w2, const float* __restrict__ em1_b2,
    const float* __restrict__ em2_w2, const float* __restrict__ em2_b2,
    const float* __restrict__ c1_lin_w, const float* __restrict__ c1_lin_b,
    const float* __restrict__ c2_lin_w, const float* __restrict__ c2_lin_b,
    const float* __restrict__ c1_w2, const float* __restrict__ c1_b2,
    const float* __restrict__ c2_w2, const float* __restrict__ c2_b2,
    const float* __restrict__ lin1_w, const float* __restrict__ lin1_b,
    const float* __restrict__ lin2_w, const float* __restrict__ lin2_b,
    float* __restrict__ fw)
{
    int idx = blockIdx.x * 256 + threadIdx.x;
    if (idx >= FOLD_TOTAL) return;
    int r = idx;
    if (r < 6144) {
        int k = r / 96, c = r % 96, i = c / 32, j = c % 32;
        float s = 0.f;
        for (int m = 0; m < 64; m++) s = fmaf(em1_w2[k * 64 + m], c1_lin_w[i * 2048 + m * 32 + j], s);
        fw[F_V1H + r] = s; return;
    }
    r -= 6144;
    if (r < 96) {
        int i = r / 32, j = r % 32;
        float s = c1_lin_b[r];
        for (int m = 0; m < 64; m++) s = fmaf(em1_b2[m], c1_lin_w[i * 2048 + m * 32 + j], s);
        fw[F_B1F + r] = s; return;
    }
    r -= 96;
    if (r < 12288) {
        int k = r / 192, c = r % 192, i = c / 64, j = c % 64;
        float s = 0.f;
        for (int m = 0; m < 64; m++) s = fmaf(em2_w2[k * 64 + m], c2_lin_w[i * 4096 + m * 64 + j], s);
        fw[F_V2H + r] = s; return;
    }
    r -= 12288;
    if (r < 192) {
        int i = r / 64, j = r % 64;
        float s = c2_lin_b[r];
        for (int m = 0; m < 64; m++) s = fmaf(em2_b2[m], c2_lin_w[i * 4096 + m * 64 + j], s);
        fw[F_B2F + r] = s; return;
    }
    r -= 192;
    if (r < 12288) {
        int i = r / 4096, k = (r / 64) % 64, j = r % 64;
        float s = 0.f;
        for (int m = 0; m < 64; m++) s = fmaf(c1_w2[i * 4096 + k * 64 + m], lin1_w[(i * 64 + m) * 64 + j], s);
        fw[F_U1 + r] = s; return;
    }
    r -= 12288;
    if (r < 64) {
        float s = lin1_b[r];
        for (int i = 0; i < 3; i++)
            for (int m = 0; m < 64; m++) s = fmaf(c1_b2[i * 64 + m], lin1_w[(i * 64 + m) * 64 + r], s);
        fw[F_UB1 + r] = s; return;
    }
    r -= 64;
    if (r < 12288) {
        int i = r / 4096, k = (r / 64) % 64, j = r % 64;
        float s = 0.f;
        for (int m = 0; m < 64; m++) s = fmaf(c2_w2[i * 4096 + k * 64 + m], lin2_w[(i * 64 + m) * 64 + j], s);
        fw[F_U2 + r] = s; return;
    }
    r -= 12288;
    {
        float s = lin2_b[r];
        for (int i = 0; i < 3; i++)
            for (int m = 0; m < 64; m++) s = fmaf(c2_b2[i * 64 + m], lin2_w[(i * 64 + m) * 64 + r], s);
        fw[F_UB2 + r] = s; return;
    }
}

// ---------------- fold2: edge-MFMA bf16 fragment weights ----------------
__global__ __launch_bounds__(256) void fold2_kernel(
    const float* __restrict__ em1_w1, const float* __restrict__ em2_w1,
    const float* __restrict__ fw, unsigned short* __restrict__ fr)
{
    int idx = blockIdx.x * 256 + threadIdx.x;
    if (idx >= FOLD2_TOTAL) return;
    if (idx < 4096) {
        const float* w = (idx < 2048) ? em1_w1 : em2_w1;
        int r = idx & 2047;
        int tt = r >> 9, lane = (r >> 3) & 63, j = r & 7;
        int q = lane >> 4, k = q * 8 + j, m = tt * 16 + (lane & 15);
        fr[idx] = (k < 16) ? bf16u(w[k * 64 + m]) : (unsigned short)0;
        return;
    }
    if (idx < 10240) {
        int r = idx - 4096;
        int nt = r / 1024, ka = (r >> 9) & 1, lane = (r >> 3) & 63, j = r & 7;
        int q = lane >> 4;
        int t = 32 * ka + 16 * (j >> 2) + 4 * q + (j & 3);
        int n = nt * 16 + (lane & 15);
        fr[idx] = bf16u(fw[F_V1H + t * 96 + n]);
        return;
    }
    {
        int r = idx - 10240;
        int nt = r / 1024, ka = (r >> 9) & 1, lane = (r >> 3) & 63, j = r & 7;
        int q = lane >> 4;
        int t = 32 * ka + 16 * (j >> 2) + 4 * q + (j & 3);
        int n = nt * 16 + (lane & 15);
        fr[idx] = bf16u(fw[F_V2H + t * 192 + n]);
        return;
    }
}

// ---------------- fold3: node-MLP MFMA fragments ----------------
__global__ __launch_bounds__(256) void fold3_kernel(
    const float* __restrict__ c1_w1, const float* __restrict__ c2_w1,
    const float* __restrict__ fw, unsigned short* __restrict__ fr2)
{
    int idx = blockIdx.x * 256 + threadIdx.x;
    if (idx >= FOLD3_TOTAL) return;
    if (idx < 6144) {
        int i = idx / 2048, r = idx % 2048;
        int tt = r >> 9, lane = (r >> 3) & 63, jj = r & 7;
        int k = (lane >> 4) * 8 + jj, m = tt * 16 + (lane & 15);
        fr2[FR3_M1W + idx] = bf16u(c1_w1[i * 2048 + k * 64 + m]);
        return;
    }
    if (idx < 18432) {
        int r = idx - 6144;
        int i = r / 4096, r2 = r % 4096;
        int b = r2 >> 10, ka = (r2 >> 9) & 1, lane = (r2 >> 3) & 63, jj = r2 & 7;
        int t = 32 * ka + 16 * (jj >> 2) + 4 * (lane >> 4) + (jj & 3);
        int n = b * 16 + (lane & 15);
        fr2[FR3_M1U + r] = bf16u(fw[F_U1 + i * 4096 + t * 64 + n]);
        return;
    }
    if (idx < 30720) {
        int r = idx - 18432;
        int i = r / 4096, r2 = r % 4096;
        int tt = r2 >> 10, ka = (r2 >> 9) & 1, lane = (r2 >> 3) & 63, jj = r2 & 7;
        int k = ka * 32 + (lane >> 4) * 8 + jj, m = tt * 16 + (lane & 15);
        fr2[FR3_M2W + r] = bf16u(c2_w1[i * 4096 + k * 64 + m]);
        return;
    }
    {
        int r = idx - 30720;
        int i = r / 4096, r2 = r % 4096;
        int b = r2 >> 10, ka = (r2 >> 9) & 1, lane = (r2 >> 3) & 63, jj = r2 & 7;
        int t = 32 * ka + 16 * (jj >> 2) + 4 * (lane >> 4) + (jj & 3);
        int n = b * 16 + (lane & 15);
        fr2[FR3_M2U + r] = bf16u(fw[F_U2 + i * 4096 + t * 64 + n]);
        return;
    }
}

// ---------------- counting sort: hist -> scan -> scatter ----------------
__global__ __launch_bounds__(256) void hist_kernel(const int* __restrict__ ei, int* __restrict__ cnt) {
    int e = blockIdx.x * 256 + threadIdx.x;
    if (e < N_EDGES) atomicAdd(&cnt[ei[N_EDGES + e]], 1);
}

__global__ __launch_bounds__(256) void scan1_kernel(const int* __restrict__ cnt,
                                                    int* __restrict__ off, int* __restrict__ bsum) {
    __shared__ int sh[256];
    int t = threadIdx.x, i = blockIdx.x * 256 + t;
    int v = (i < N_NODES) ? cnt[i] : 0;
    sh[t] = v; __syncthreads();
    for (int d = 1; d < 256; d <<= 1) {
        int add = (t >= d) ? sh[t - d] : 0;
        __syncthreads();
        sh[t] += add;
        __syncthreads();
    }
    if (i < N_NODES) off[i] = sh[t] - v;
    if (t == 255) bsum[blockIdx.x] = sh[255];
}

__global__ __launch_bounds__(256) void scan2_kernel(int* __restrict__ bsum) {
    __shared__ int sh[256];
    int t = threadIdx.x;
    int v = (t < 196) ? bsum[t] : 0;
    sh[t] = v; __syncthreads();
    for (int d = 1; d < 256; d <<= 1) {
        int add = (t >= d) ? sh[t - d] : 0;
        __syncthreads();
        sh[t] += add;
        __syncthreads();
    }
    bsum[t] = sh[t] - v;
}

__global__ __launch_bounds__(256) void scan3_kernel(int* __restrict__ off, const int* __restrict__ bsum,
                                                    int* __restrict__ cur) {
    int i = blockIdx.x * 256 + threadIdx.x;
    if (i < N_NODES) {
        int o = off[i] + bsum[i >> 8];
        off[i] = o;
        cur[i] = o;
    }
    if (i == 0) off[N_NODES] = N_EDGES;
}

__global__ __launch_bounds__(256) void scatter_kernel(const int* __restrict__ ei, int* __restrict__ cur,
                                                      int* __restrict__ ssrc, int* __restrict__ seid) {
    int e = blockIdx.x * 256 + threadIdx.x;
    if (e >= N_EDGES) return;
    int d = ei[N_EDGES + e];
    int p = atomicAdd(&cur[d], 1);
    ssrc[p] = ei[e];
    seid[p] = e;
}

// ---------------- MFMA edge projection (q stored as fp8 e4m3 pairs) ----------------
template<int NT>
__global__ __launch_bounds__(256, 2) void edge_mfma_kernel(
    const float* __restrict__ edge_attr, const int* __restrict__ seid,
    const unsigned short* __restrict__ w1frag, const float* __restrict__ b1,
    const unsigned short* __restrict__ vfrag,  const float* __restrict__ bias2,
    unsigned short* __restrict__ qout, int tile0, int nTiles)
{
    const int lane = threadIdx.x & 63;
    const int wid  = threadIdx.x >> 6;
    const int col  = lane & 15;
    const int quad = lane >> 4;

    bf16x8 w1f[4];
#pragma unroll
    for (int tt = 0; tt < 4; tt++)
        w1f[tt] = *(const bf16x8*)(w1frag + (tt * 64 + lane) * 8);
    bf16x8 vf[NT][2];
#pragma unroll
    for (int nt = 0; nt < NT; nt++)
#pragma unroll
        for (int ka = 0; ka < 2; ka++)
            vf[nt][ka] = *(const bf16x8*)(vfrag + ((nt * 2 + ka) * 64 + lane) * 8);
    float4 b1v[4];
#pragma unroll
    for (int tt = 0; tt < 4; tt++)
        b1v[tt] = *(const float4*)(b1 + tt * 16 + quad * 4);
    float b2v[NT];
#pragma unroll
    for (int nt = 0; nt < NT; nt++) b2v[nt] = bias2[nt * 16 + col];

    const int gw = blockIdx.x * 4 + wid;
    const int stride = gridDim.x * 4;
    for (int t = gw; t < nTiles; t += stride) {
        const int s = (tile0 + t) * 16 + col;
        const int e = seid[s];
        bf16x8 eaf;
        uint4 eau = make_uint4(0u, 0u, 0u, 0u);
        if (quad < 2) {
            const float4 v0 = *(const float4*)(edge_attr + (size_t)e * 16 + quad * 8);
            const float4 v1 = *(const float4*)(edge_attr + (size_t)e * 16 + quad * 8 + 4);
            eau.x = packbf2(v0.x, v0.y); eau.y = packbf2(v0.z, v0.w);
            eau.z = packbf2(v1.x, v1.y); eau.w = packbf2(v1.z, v1.w);
        }
        eaf = __builtin_bit_cast(bf16x8, eau);

        f32x4 c1[4];
#pragma unroll
        for (int tt = 0; tt < 4; tt++) {
            f32x4 ci = {b1v[tt].x, b1v[tt].y, b1v[tt].z, b1v[tt].w};
            c1[tt] = __builtin_amdgcn_mfma_f32_16x16x32_bf16(w1f[tt], eaf, ci, 0, 0, 0);
        }

        bf16x8 a2[2];
#pragma unroll
        for (int ka = 0; ka < 2; ka++) {
            uint4 au;
            au.x = packbf2(fmaxf(c1[2 * ka][0], 0.f),     fmaxf(c1[2 * ka][1], 0.f));
            au.y = packbf2(fmaxf(c1[2 * ka][2], 0.f),     fmaxf(c1[2 * ka][3], 0.f));
            au.z = packbf2(fmaxf(c1[2 * ka + 1][0], 0.f), fmaxf(c1[2 * ka + 1][1], 0.f));
            au.w = packbf2(fmaxf(c1[2 * ka + 1][2], 0.f), fmaxf(c1[2 * ka + 1][3], 0.f));
            a2[ka] = __builtin_bit_cast(bf16x8, au);
        }

        f32x4 c2[NT];
#pragma unroll
        for (int nt = 0; nt < NT; nt++) {
            f32x4 ci = {b2v[nt], b2v[nt], b2v[nt], b2v[nt]};
            ci = __builtin_amdgcn_mfma_f32_16x16x32_bf16(a2[0], vf[nt][0], ci, 0, 0, 0);
            c2[nt] = __builtin_amdgcn_mfma_f32_16x16x32_bf16(a2[1], vf[nt][1], ci, 0, 0, 0);
        }

        const size_t rowb = (size_t)t * 16 + quad * 4;
#pragma unroll
        for (int b = 0; b < NT / 2; b++) {
#pragma unroll
            for (int r = 0; r < 4; r++) {
                qout[(rowb + r) * (size_t)(NT * 8) + b * 16 + col] =
                    pkfp8(c2[2 * b][r], c2[2 * b + 1][r]);
            }
        }
    }
}

// ---------------- gather layer 1: 2-edge unrolled; writes agg1[N][96] TRUE col order ----------------
__global__ __launch_bounds__(64) void gather1_kernel(
    const float* __restrict__ x, const int* __restrict__ off, const int* __restrict__ ssrc,
    const unsigned short* __restrict__ q1, float* __restrict__ agg1)
{
    const int n = blockIdx.x, l = threadIdx.x;
    if (l >= 48) return;
    const int s0 = off[n], s1 = off[n + 1];
    const int c = l & 15;
    const int n1 = (l >> 4) * 32 + c, n2 = n1 + 16;
    float a0 = 0.f, a1 = 0.f, b0 = 0.f, b1 = 0.f;
    int s = s0;
    for (; s + 2 <= s1; s += 2) {
        const int srcA = ssrc[s], srcB = ssrc[s + 1];
        const unsigned short uA = q1[(size_t)s * 48 + l];
        const unsigned short uB = q1[(size_t)(s + 1) * 48 + l];
        const float xA0 = x[(size_t)srcA * 32 + c], xA1 = x[(size_t)srcA * 32 + c + 16];
        const float xB0 = x[(size_t)srcB * 32 + c], xB1 = x[(size_t)srcB * 32 + c + 16];
        const f32x2 dA = unpkfp8(uA);
        const f32x2 dB = unpkfp8(uB);
        a0 += fmaxf(xA0 + dA.x, 0.f);
        a1 += fmaxf(xA1 + dA.y, 0.f);
        b0 += fmaxf(xB0 + dB.x, 0.f);
        b1 += fmaxf(xB1 + dB.y, 0.f);
    }
    if (s < s1) {
        const int src = ssrc[s];
        const f32x2 d = unpkfp8(q1[(size_t)s * 48 + l]);
        a0 += fmaxf(x[(size_t)src * 32 + c] + d.x, 0.f);
        a1 += fmaxf(x[(size_t)src * 32 + c + 16] + d.y, 0.f);
    }
    agg1[(size_t)n * 96 + n1] = a0 + b0;
    agg1[(size_t)n * 96 + n2] = a1 + b1;
}

// ---------------- node MLP layer 1 via MFMA (16 nodes per wave) ----------------
__global__ __launch_bounds__(256) void mlp1_mfma_kernel(
    const float* __restrict__ x, const float* __restrict__ agg1,
    const unsigned short* __restrict__ fr2, const float* __restrict__ c1_b1,
    const float* __restrict__ fw, float* __restrict__ h1)
{
    const int lane = threadIdx.x & 63, wid = threadIdx.x >> 6;
    const int tile = blockIdx.x * 4 + wid;
    if (tile >= NTILES) return;
    const int col = lane & 15, quad = lane >> 4;
    const int node = tile * 16 + col;

    const float4 xa = *(const float4*)(x + (size_t)node * 32 + quad * 8);
    const float4 xb = *(const float4*)(x + (size_t)node * 32 + quad * 8 + 4);

    f32x4 c2[4];
#pragma unroll
    for (int b = 0; b < 4; b++) {
        const float ub = fw[F_UB1 + b * 16 + col];
        c2[b] = {ub, ub, ub, ub};
    }
#pragma unroll
    for (int i = 0; i < 3; i++) {
        const float4 a0 = *(const float4*)(agg1 + (size_t)node * 96 + i * 32 + quad * 8);
        const float4 a1 = *(const float4*)(agg1 + (size_t)node * 96 + i * 32 + quad * 8 + 4);
        uint4 iu;
        iu.x = packbf2(xa.x + a0.x, xa.y + a0.y);
        iu.y = packbf2(xa.z + a0.z, xa.w + a0.w);
        iu.z = packbf2(xb.x + a1.x, xb.y + a1.y);
        iu.w = packbf2(xb.z + a1.z, xb.w + a1.w);
        const bf16x8 inf = __builtin_bit_cast(bf16x8, iu);

        f32x4 c1[4];
#pragma unroll
        for (int tt = 0; tt < 4; tt++) {
            const bf16x8 wf = *(const bf16x8*)(fr2 + FR3_M1W + ((i * 4 + tt) * 64 + lane) * 8);
            const float4 bi = *(const float4*)(c1_b1 + i * 64 + tt * 16 + quad * 4);
            f32x4 ci = {bi.x, bi.y, bi.z, bi.w};
            c1[tt] = __builtin_amdgcn_mfma_f32_16x16x32_bf16(wf, inf, ci, 0, 0, 0);
        }
        bf16x8 a2[2];
#pragma unroll
        for (int ka = 0; ka < 2; ka++) {
            uint4 au;
            au.x = packbf2(fmaxf(c1[2 * ka][0], 0.f),     fmaxf(c1[2 * ka][1], 0.f));
            au.y = packbf2(fmaxf(c1[2 * ka][2], 0.f),     fmaxf(c1[2 * ka][3], 0.f));
            au.z = packbf2(fmaxf(c1[2 * ka + 1][0], 0.f), fmaxf(c1[2 * ka + 1][1], 0.f));
            au.w = packbf2(fmaxf(c1[2 * ka + 1][2], 0.f), fmaxf(c1[2 * ka + 1][3], 0.f));
            a2[ka] = __builtin_bit_cast(bf16x8, au);
        }
#pragma unroll
        for (int b = 0; b < 4; b++)
#pragma unroll
            for (int ka = 0; ka < 2; ka++) {
                const bf16x8 uf = *(const bf16x8*)(fr2 + FR3_M1U + (((i * 4 + b) * 2 + ka) * 64 + lane) * 8);
                c2[b] = __builtin_amdgcn_mfma_f32_16x16x32_bf16(a2[ka], uf, c2[b], 0, 0, 0);
            }
    }
    const int rowb = tile * 16 + quad * 4;
#pragma unroll
    for (int b = 0; b < 4; b++)
#pragma unroll
        for (int r = 0; r < 4; r++)
            h1[(size_t)(rowb + r) * 64 + b * 16 + col] = fmaxf(c2[b][r], 0.f);
}

// ---------------- gather layer 2 (chunked; 2-edge unrolled; chunk0 writes) ----------------
__global__ __launch_bounds__(64) void gather2_kernel(
    const float* __restrict__ h1, const int* __restrict__ off, const int* __restrict__ ssrc,
    const unsigned short* __restrict__ q2, float* __restrict__ agg2, int lo, int hi, int first)
{
    const int n = blockIdx.x, l = threadIdx.x;
    int s0 = off[n], s1 = off[n + 1];
    if (s0 < lo) s0 = lo;
    if (s1 > hi) s1 = hi;
    if (!first && s0 >= s1) return;

    const int k1 = ((l >> 4) & 1) * 32 + (l & 15);
    float sa0 = 0.f, sa1 = 0.f, sb0 = 0.f, sb1 = 0.f;
    float ta0 = 0.f, ta1 = 0.f, tb0 = 0.f, tb1 = 0.f;
    int s = s0;
    for (; s + 2 <= s1; s += 2) {
        const int srcA = ssrc[s], srcB = ssrc[s + 1];
        const float hA0 = h1[(size_t)srcA * 64 + k1];
        const float hA1 = h1[(size_t)srcA * 64 + k1 + 16];
        const float hB0 = h1[(size_t)srcB * 64 + k1];
        const float hB1 = h1[(size_t)srcB * 64 + k1 + 16];
        const f32x2 dA = unpkfp8(q2[(size_t)(s - lo) * 96 + l]);
        const f32x2 dB = unpkfp8(q2[(size_t)(s + 1 - lo) * 96 + l]);
        sa0 += fmaxf(hA0 + dA.x, 0.f);
        sa1 += fmaxf(hA1 + dA.y, 0.f);
        ta0 += fmaxf(hB0 + dB.x, 0.f);
        ta1 += fmaxf(hB1 + dB.y, 0.f);
        if (l < 32) {
            const f32x2 d2A = unpkfp8(q2[(size_t)(s - lo) * 96 + 64 + l]);
            const f32x2 d2B = unpkfp8(q2[(size_t)(s + 1 - lo) * 96 + 64 + l]);
            sb0 += fmaxf(hA0 + d2A.x, 0.f);
            sb1 += fmaxf(hA1 + d2A.y, 0.f);
            tb0 += fmaxf(hB0 + d2B.x, 0.f);
            tb1 += fmaxf(hB1 + d2B.y, 0.f);
        }
    }
    if (s < s1) {
        const int src = ssrc[s];
        const float hv0 = h1[(size_t)src * 64 + k1];
        const float hv1 = h1[(size_t)src * 64 + k1 + 16];
        const f32x2 d = unpkfp8(q2[(size_t)(s - lo) * 96 + l]);
        sa0 += fmaxf(hv0 + d.x, 0.f);
        sa1 += fmaxf(hv1 + d.y, 0.f);
        if (l < 32) {
            const f32x2 d2 = unpkfp8(q2[(size_t)(s - lo) * 96 + 64 + l]);
            sb0 += fmaxf(hv0 + d2.x, 0.f);
            sb1 += fmaxf(hv1 + d2.y, 0.f);
        }
    }
    sa0 += ta0; sa1 += ta1; sb0 += tb0; sb1 += tb1;
    const int C1 = 32 * (l >> 4) + (l & 15);
    const int C2 = 128 + 32 * (l >> 4) + (l & 15);
    float* row = agg2 + (size_t)n * 192;
    if (first) {
        row[C1] = sa0; row[C1 + 16] = sa1;
        if (l < 32) { row[C2] = sb0; row[C2 + 16] = sb1; }
    } else {
        row[C1] += sa0; row[C1 + 16] += sa1;
        if (l < 32) { row[C2] += sb0; row[C2 + 16] += sb1; }
    }
}

// ---------------- node MLP layer 2 via MFMA (16 nodes per wave) ----------------
__global__ __launch_bounds__(256) void mlp2_mfma_kernel(
    const float* __restrict__ h1, const float* __restrict__ agg2,
    const unsigned short* __restrict__ fr2, const float* __restrict__ c2_b1,
    const float* __restrict__ fw, float* __restrict__ h2)
{
    const int lane = threadIdx.x & 63, wid = threadIdx.x >> 6;
    const int tile = blockIdx.x * 4 + wid;
    if (tile >= NTILES) return;
    const int col = lane & 15, quad = lane >> 4;
    const int node = tile * 16 + col;

    float4 hv[4];
#pragma unroll
    for (int p = 0; p < 4; p++)
        hv[p] = *(const float4*)(h1 + (size_t)node * 64 + (p >> 1) * 32 + quad * 8 + (p & 1) * 4);

    f32x4 c2[4];
#pragma unroll
    for (int b = 0; b < 4; b++) {
        const float ub = fw[F_UB2 + b * 16 + col];
        c2[b] = {ub, ub, ub, ub};
    }
#pragma unroll
    for (int i = 0; i < 3; i++) {
        bf16x8 inf[2];
#pragma unroll
        for (int ka = 0; ka < 2; ka++) {
            const float4 a0 = *(const float4*)(agg2 + (size_t)node * 192 + i * 64 + ka * 32 + quad * 8);
            const float4 a1 = *(const float4*)(agg2 + (size_t)node * 192 + i * 64 + ka * 32 + quad * 8 + 4);
            const float4 h0 = hv[ka * 2], h1v = hv[ka * 2 + 1];
            uint4 iu;
            iu.x = packbf2(h0.x + a0.x, h0.y + a0.y);
            iu.y = packbf2(h0.z + a0.z, h0.w + a0.w);
            iu.z = packbf2(h1v.x + a1.x, h1v.y + a1.y);
            iu.w = packbf2(h1v.z + a1.z, h1v.w + a1.w);
            inf[ka] = __builtin_bit_cast(bf16x8, iu);
        }
        f32x4 c1[4];
#pragma unroll
        for (int tt = 0; tt < 4; tt++) {
            const bf16x8 wf0 = *(const bf16x8*)(fr2 + FR3_M2W + (((i * 4 + tt) * 2 + 0) * 64 + lane) * 8);
            const bf16x8 wf1 = *(const bf16x8*)(fr2 + FR3_M2W + (((i * 4 + tt) * 2 + 1) * 64 + lane) * 8);
            const float4 bi = *(const float4*)(c2_b1 + i * 64 + tt * 16 + quad * 4);
            f32x4 ci = {bi.x, bi.y, bi.z, bi.w};
            ci = __builtin_amdgcn_mfma_f32_16x16x32_bf16(wf0, inf[0], ci, 0, 0, 0);
            c1[tt] = __builtin_amdgcn_mfma_f32_16x16x32_bf16(wf1, inf[1], ci, 0, 0, 0);
        }
        bf16x8 a2[2];
#pragma unroll
        for (int ka = 0; ka < 2; ka++) {
            uint4 au;
            au.x = packbf2(fmaxf(c1[2 * ka][0], 0.f),     fmaxf(c1[2 * ka][1], 0.f));
            au.y = packbf2(fmaxf(c1[2 * ka][2], 0.f),     fmaxf(c1[2 * ka][3], 0.f));
            au.z = packbf2(fmaxf(c1[2 * ka + 1][0], 0.f), fmaxf(c1[2 * ka + 1][1], 0.f));
            au.w = packbf2(fmaxf(c1[2 * ka + 1][2], 0.f), fmaxf(c1[2 * ka + 1][3], 0.f));
            a2[ka] = __builtin_bit_cast(bf16x8, au);
        }
#pragma unroll
        for (int b = 0; b < 4; b++)
#pragma unroll
            for (int ka = 0; ka < 2; ka++) {
                const bf16x8 uf = *(const bf16x8*)(fr2 + FR3_M2U + (((i * 4 + b) * 2 + ka) * 64 + lane) * 8);
                c2[b] = __builtin_amdgcn_mfma_f32_16x16x32_bf16(a2[ka], uf, c2[b], 0, 0, 0);
            }
    }
    const int rowb = tile * 16 + quad * 4;
#pragma unroll
    for (int b = 0; b < 4; b++)
#pragma unroll
        for (int r = 0; r < 4; r++)
            h2[(size_t)(rowb + r) * 64 + b * 16 + col] = fmaxf(c2[b][r], 0.f);
}

// ---------------- pooling + head (fused; batch is sorted) ----------------
__global__ __launch_bounds__(256) void pool_kernel(
    const float* __restrict__ h2, const int* __restrict__ batch,
    const float* __restrict__ u, const float* __restrict__ fc_w,
    const float* __restrict__ fc_b, float* __restrict__ out)
{
    __shared__ float red[256];
    const int g = blockIdx.x, t = threadIdx.x;
    int lo = 0, hi = N_NODES;
    while (lo < hi) { int m = (lo + hi) >> 1; if (batch[m] < g) lo = m + 1; else hi = m; }
    int lo2 = lo, hi2 = N_NODES;
    while (lo2 < hi2) { int m = (lo2 + hi2) >> 1; if (batch[m] < g + 1) lo2 = m + 1; else hi2 = m; }

    const int col = t & 63, ch = t >> 6;
    float s = 0.f;
    for (int idx = lo + ch; idx < lo2; idx += 4) s += h2[(size_t)idx * 64 + col];
    red[t] = s;
    __syncthreads();
    if (t < 64) red[t] = red[t] + red[64 + t] + red[128 + t] + red[192 + t];
    __syncthreads();
    if (t == 0) {
        const float inv = 1.f / fmaxf((float)(lo2 - lo), 1.f);
        float sv = fc_b[0];
        for (int j = 0; j < 64; j++) sv = fmaf(red[j] * inv, fc_w[j], sv);
        for (int k = 0; k < 32; k++) sv = fmaf(u[(size_t)g * 32 + k], fc_w[64 + k], sv);
        out[g] = sv;
    }
}

extern "C" void kernel_launch(void* const* d_in, const int* in_sizes, int n_in,
                              void* d_out, int out_size, void* d_ws, size_t ws_size,
                              hipStream_t stream) {
    (void)in_sizes; (void)n_in; (void)out_size; (void)ws_size;
    const float* x        = (const float*)d_in[0];
    const float* edge_attr= (const float*)d_in[1];
    const float* u        = (const float*)d_in[2];
    const float* em1_w1   = (const float*)d_in[3];
    const float* em1_b1   = (const float*)d_in[4];
    const float* em1_w2   = (const float*)d_in[5];
    const float* em1_b2   = (const float*)d_in[6];
    const float* em2_w1   = (const float*)d_in[7];
    const float* em2_b1   = (const float*)d_in[8];
    const float* em2_w2   = (const float*)d_in[9];
    const float* em2_b2   = (const float*)d_in[10];
    const float* c1_lin_w = (const float*)d_in[11];
    const float* c1_lin_b = (const float*)d_in[12];
    const float* c1_w1    = (const float*)d_in[13];
    const float* c1_b1    = (const float*)d_in[14];
    const float* c1_w2    = (const float*)d_in[15];
    const float* c1_b2    = (const float*)d_in[16];
    const float* c2_lin_w = (const float*)d_in[17];
    const float* c2_lin_b = (const float*)d_in[18];
    const float* c2_w1    = (const float*)d_in[19];
    const float* c2_b1    = (const float*)d_in[20];
    const float* c2_w2    = (const float*)d_in[21];
    const float* c2_b2    = (const float*)d_in[22];
    const float* lin1_w   = (const float*)d_in[23];
    const float* lin1_b   = (const float*)d_in[24];
    const float* lin2_w   = (const float*)d_in[25];
    const float* lin2_b   = (const float*)d_in[26];
    const float* fc_w     = (const float*)d_in[27];
    const float* fc_b     = (const float*)d_in[28];
    const int*   ei       = (const int*)d_in[29];
    const int*   batch    = (const int*)d_in[30];

    char* wsb = (char*)d_ws;
    int*   cnt  = (int*)(wsb + B_CNT);
    int*   off  = (int*)(wsb + B_OFF);
    int*   cur  = (int*)(wsb + B_CUR);
    int*   bsum = (int*)(wsb + B_BSUM);
    int*   ssrc = (int*)(wsb + B_SSRC);
    int*   seid = (int*)(wsb + B_SEID);
    float* agg2 = (float*)(wsb + B_AGG2);   // also used as agg1 [N][96]
    unsigned short* q = (unsigned short*)(wsb + B_Q);
    float* h1   = (float*)(wsb + B_H1);
    float* h2   = (float*)(wsb + B_H2);
    float* fw   = (float*)(wsb + B_FOLD);
    unsigned short* fr  = (unsigned short*)(wsb + B_FRAG);
    unsigned short* fr2 = (unsigned short*)(wsb + B_FR2);
    float* out  = (float*)d_out;

    (void)hipMemsetAsync(d_ws, 0, ZERO_BYTES, stream);   // histogram counters only

    fold_kernel<<<(FOLD_TOTAL + 255) / 256, 256, 0, stream>>>(
        em1_w2, em1_b2, em2_w2, em2_b2, c1_lin_w, c1_lin_b, c2_lin_w, c2_lin_b,
        c1_w2, c1_b2, c2_w2, c2_b2, lin1_w, lin1_b, lin2_w, lin2_b, fw);
    fold2_kernel<<<(FOLD2_TOTAL + 255) / 256, 256, 0, stream>>>(em1_w1, em2_w1, fw, fr);
    fold3_kernel<<<(FOLD3_TOTAL + 255) / 256, 256, 0, stream>>>(c1_w1, c2_w1, fw, fr2);

    // counting sort by dst
    hist_kernel<<<N_EDGES / 256, 256, 0, stream>>>(ei, cnt);
    scan1_kernel<<<196, 256, 0, stream>>>(cnt, off, bsum);
    scan2_kernel<<<1, 256, 0, stream>>>(bsum);
    scan3_kernel<<<196, 256, 0, stream>>>(off, bsum, cur);
    scatter_kernel<<<N_EDGES / 256, 256, 0, stream>>>(ei, cur, ssrc, seid);

    // layer 1
    edge_mfma_kernel<6><<<2048, 256, 0, stream>>>(
        edge_attr, seid, fr + FR_W1E1, em1_b1, fr + FR_V1, fw + F_B1F, q, 0, N_EDGES / 16);
    gather1_kernel<<<N_NODES, 64, 0, stream>>>(x, off, ssrc, q, agg2);
    mlp1_mfma_kernel<<<(NTILES + 3) / 4, 256, 0, stream>>>(x, agg2, fr2, c1_b1, fw, h1);

    // layer 2 (two chunks, q buffer reused)
    for (int c = 0; c < 2; c++) {
        const int lo = c * ECHUNK, hi = lo + ECHUNK;
        edge_mfma_kernel<12><<<1024, 256, 0, stream>>>(
            edge_attr, seid, fr + FR_W1E2, em2_b1, fr + FR_V2, fw + F_B2F, q,
            lo / 16, ECHUNK / 16);
        gather2_kernel<<<N_NODES, 64, 0, stream>>>(h1, off, ssrc, q, agg2, lo, hi, c == 0 ? 1 : 0);
    }
    mlp2_mfma_kernel<<<(NTILES + 3) / 4, 256, 0, stream>>>(h1, agg2, fr2, c2_b1, fw, h2);

    // pooling + head (fused)
    pool_kernel<<<N_GRAPHS, 256, 0, stream>>>(h2, batch, u, fc_w, fc_b, out);
}

// Round 11
// 488.704 us; speedup vs baseline: 1.2039x; 1.0301x over previous
//
#include <hip/hip_runtime.h>
#include <hip/hip_bf16.h>

#define N_NODES  50000
#define N_EDGES  800000
#define N_GRAPHS 512
#define NTILES   3125   // N_NODES / 16

typedef short bf16x8 __attribute__((ext_vector_type(8)));
typedef float f32x4  __attribute__((ext_vector_type(4)));
typedef float f32x2  __attribute__((ext_vector_type(2)));

// ---------------- workspace layout (BYTE offsets, 256-aligned) ----------------
constexpr size_t B_CNT  = 0;                 // N ints (zeroed)
constexpr size_t ZERO_BYTES = 200192;
constexpr size_t B_OFF  = 200192;            // (N+1) ints
constexpr size_t B_CUR  = 400384;            // N ints
constexpr size_t B_BSUM = 600576;            // 256 ints
constexpr size_t B_SEDGE= 601600;            // E int2 (src, eid) of sorted edge — 6.4 MB
constexpr size_t B_FR2  = 7001600;           // mlp MFMA frags, 43008 ushorts
constexpr size_t B_AGG2 = 7134720;           // N*192 f; also aliased as agg1 [N][96]
constexpr size_t B_Q    = 45534720;          // fp8 q: q1[E][48]u16 | q2[E][96]u16 (153.6MB)
constexpr size_t B_H1   = 199134720;         // N*64 f
constexpr size_t B_H2   = 211934720;         // N*64 f
constexpr size_t B_FOLD = 224734720;         // folded weights, 43424 floats
constexpr size_t B_FRAG = 224908416;         // bf16 edge-MFMA fragment weights (22528 ushorts)
// fold-region float offsets
constexpr int F_V1H = 0;      // [64][96]   V1[t][n]
constexpr int F_B1F = 6144;   // [96]
constexpr int F_V2H = 6240;   // [64][192]  V2[t][n]
constexpr int F_B2F = 18528;  // [192]
constexpr int F_U1  = 18720;  // [3][64][64]
constexpr int F_UB1 = 31008;  // [64]
constexpr int F_U2  = 31072;  // [3][64][64]
constexpr int F_UB2 = 43360;  // [64]
constexpr int FOLD_TOTAL = 43424;
// edge frag-region ushort offsets
constexpr int FR_W1E1 = 0;      // [4][64][8]   em1_w1^T A-frags (K padded 16->32)
constexpr int FR_W1E2 = 2048;   // [4][64][8]
constexpr int FR_V1   = 4096;   // [6][2][64][8]  V1 B-frags, k-permuted
constexpr int FR_V2   = 10240;  // [12][2][64][8] V2 B-frags, k-permuted
constexpr int FOLD2_TOTAL = 22528;
// mlp frag-region (fr2) ushort offsets
constexpr int FR3_M1W = 0;      // [3][4][64][8]     c1_w1^T A-frags (K=32)
constexpr int FR3_M1U = 6144;   // [3][4][2][64][8]  U1 B-frags, k-permuted
constexpr int FR3_M2W = 18432;  // [3][4][2][64][8]  c2_w1^T A-frags (K=64)
constexpr int FR3_M2U = 30720;  // [3][4][2][64][8]  U2 B-frags, k-permuted
constexpr int FOLD3_TOTAL = 43008;

__device__ inline unsigned short bf16u(float x) {
    unsigned int ua = __float_as_uint(x);
    return (unsigned short)((ua + 0x7FFFu + ((ua >> 16) & 1u)) >> 16);
}
__device__ inline unsigned int packbf2(float a, float b) {
    unsigned int ua = __float_as_uint(a), ub = __float_as_uint(b);
    return ((ua + 0x7FFFu + ((ua >> 16) & 1u)) >> 16) |
           ((ub + 0x7FFFu + ((ub >> 16) & 1u)) & 0xFFFF0000u);
}
// fp8 e4m3 pack/unpack (HW cvt; OCP on gfx950). Pair layout: byte0=a, byte1=b.
__device__ inline unsigned short pkfp8(float a, float b) {
    return (unsigned short)__builtin_amdgcn_cvt_pk_fp8_f32(a, b, 0, false);
}
__device__ inline f32x2 unpkfp8(unsigned short us) {
    return __builtin_amdgcn_cvt_pk_f32_fp8((int)us, false);
}

// ---------------- fold: precompute folded weight products (fp32) ----------------
__global__ __launch_bounds__(256) void fold_kernel(
    const float* __restrict__ em1_w2, const float* __restrict__ em1_b2,
    const float* __restrict__ em2_w2, const float* __restrict__ em2_b2,
    const float* __restrict__ c1_lin_w, const float* __restrict__ c1_lin_b,
    const float* __restrict__ c2_lin_w, const float* __restrict__ c2_lin_b,
    const float* __restrict__ c1_w2, const float* __restrict__ c1_b2,
    const float* __restrict__ c2_w2, const float* __restrict__ c2_b2,
    const float* __restrict__ lin1_w, const float* __restrict__ lin1_b,
    const float* __restrict__ lin2_w, const float* __restrict__ lin2_b,
    float* __restrict__ fw)
{
    int idx = blockIdx.x * 256 + threadIdx.x;
    if (idx >= FOLD_TOTAL) return;
    int r = idx;
    if (r < 6144) {
        int k = r / 96, c = r % 96, i = c / 32, j = c % 32;
        float s = 0.f;
        for (int m = 0; m < 64; m++) s = fmaf(em1_w2[k * 64 + m], c1_lin_w[i * 2048 + m * 32 + j], s);
        fw[F_V1H + r] = s; return;
    }
    r -= 6144;
    if (r < 96) {
        int i = r / 32, j = r % 32;
        float s = c1_lin_b[r];
        for (int m = 0; m < 64; m++) s = fmaf(em1_b2[m], c1_lin_w[i * 2048 + m * 32 + j], s);
        fw[F_B1F + r] = s; return;
    }
    r -= 96;
    if (r < 12288) {
        int k = r / 192, c = r % 192, i = c / 64, j = c % 64;
        float s = 0.f;
        for (int m = 0; m < 64; m++) s = fmaf(em2_w2[k * 64 + m], c2_lin_w[i * 4096 + m * 64 + j], s);
        fw[F_V2H + r] = s; return;
    }
    r -= 12288;
    if (r < 192) {
        int i = r / 64, j = r % 64;
        float s = c2_lin_b[r];
        for (int m = 0; m < 64; m++) s = fmaf(em2_b2[m], c2_lin_w[i * 4096 + m * 64 + j], s);
        fw[F_B2F + r] = s; return;
    }
    r -= 192;
    if (r < 12288) {
        int i = r / 4096, k = (r / 64) % 64, j = r % 64;
        float s = 0.f;
        for (int m = 0; m < 64; m++) s = fmaf(c1_w2[i * 4096 + k * 64 + m], lin1_w[(i * 64 + m) * 64 + j], s);
        fw[F_U1 + r] = s; return;
    }
    r -= 12288;
    if (r < 64) {
        float s = lin1_b[r];
        for (int i = 0; i < 3; i++)
            for (int m = 0; m < 64; m++) s = fmaf(c1_b2[i * 64 + m], lin1_w[(i * 64 + m) * 64 + r], s);
        fw[F_UB1 + r] = s; return;
    }
    r -= 64;
    if (r < 12288) {
        int i = r / 4096, k = (r / 64) % 64, j = r % 64;
        float s = 0.f;
        for (int m = 0; m < 64; m++) s = fmaf(c2_w2[i * 4096 + k * 64 + m], lin2_w[(i * 64 + m) * 64 + j], s);
        fw[F_U2 + r] = s; return;
    }
    r -= 12288;
    {
        float s = lin2_b[r];
        for (int i = 0; i < 3; i++)
            for (int m = 0; m < 64; m++) s = fmaf(c2_b2[i * 64 + m], lin2_w[(i * 64 + m) * 64 + r], s);
        fw[F_UB2 + r] = s; return;
    }
}

// ---------------- fold2: edge-MFMA bf16 fragment weights ----------------
__global__ __launch_bounds__(256) void fold2_kernel(
    const float* __restrict__ em1_w1, const float* __restrict__ em2_w1,
    const float* __restrict__ fw, unsigned short* __restrict__ fr)
{
    int idx = blockIdx.x * 256 + threadIdx.x;
    if (idx >= FOLD2_TOTAL) return;
    if (idx < 4096) {
        const float* w = (idx < 2048) ? em1_w1 : em2_w1;
        int r = idx & 2047;
        int tt = r >> 9, lane = (r >> 3) & 63, j = r & 7;
        int q = lane >> 4, k = q * 8 + j, m = tt * 16 + (lane & 15);
        fr[idx] = (k < 16) ? bf16u(w[k * 64 + m]) : (unsigned short)0;
        return;
    }
    if (idx < 10240) {
        int r = idx - 4096;
        int nt = r / 1024, ka = (r >> 9) & 1, lane = (r >> 3) & 63, j = r & 7;
        int q = lane >> 4;
        int t = 32 * ka + 16 * (j >> 2) + 4 * q + (j & 3);
        int n = nt * 16 + (lane & 15);
        fr[idx] = bf16u(fw[F_V1H + t * 96 + n]);
        return;
    }
    {
        int r = idx - 10240;
        int nt = r / 1024, ka = (r >> 9) & 1, lane = (r >> 3) & 63, j = r & 7;
        int q = lane >> 4;
        int t = 32 * ka + 16 * (j >> 2) + 4 * q + (j & 3);
        int n = nt * 16 + (lane & 15);
        fr[idx] = bf16u(fw[F_V2H + t * 192 + n]);
        return;
    }
}

// ---------------- fold3: node-MLP MFMA fragments ----------------
__global__ __launch_bounds__(256) void fold3_kernel(
    const float* __restrict__ c1_w1, const float* __restrict__ c2_w1,
    const float* __restrict__ fw, unsigned short* __restrict__ fr2)
{
    int idx = blockIdx.x * 256 + threadIdx.x;
    if (idx >= FOLD3_TOTAL) return;
    if (idx < 6144) {
        int i = idx / 2048, r = idx % 2048;
        int tt = r >> 9, lane = (r >> 3) & 63, jj = r & 7;
        int k = (lane >> 4) * 8 + jj, m = tt * 16 + (lane & 15);
        fr2[FR3_M1W + idx] = bf16u(c1_w1[i * 2048 + k * 64 + m]);
        return;
    }
    if (idx < 18432) {
        int r = idx - 6144;
        int i = r / 4096, r2 = r % 4096;
        int b = r2 >> 10, ka = (r2 >> 9) & 1, lane = (r2 >> 3) & 63, jj = r2 & 7;
        int t = 32 * ka + 16 * (jj >> 2) + 4 * (lane >> 4) + (jj & 3);
        int n = b * 16 + (lane & 15);
        fr2[FR3_M1U + r] = bf16u(fw[F_U1 + i * 4096 + t * 64 + n]);
        return;
    }
    if (idx < 30720) {
        int r = idx - 18432;
        int i = r / 4096, r2 = r % 4096;
        int tt = r2 >> 10, ka = (r2 >> 9) & 1, lane = (r2 >> 3) & 63, jj = r2 & 7;
        int k = ka * 32 + (lane >> 4) * 8 + jj, m = tt * 16 + (lane & 15);
        fr2[FR3_M2W + r] = bf16u(c2_w1[i * 4096 + k * 64 + m]);
        return;
    }
    {
        int r = idx - 30720;
        int i = r / 4096, r2 = r % 4096;
        int b = r2 >> 10, ka = (r2 >> 9) & 1, lane = (r2 >> 3) & 63, jj = r2 & 7;
        int t = 32 * ka + 16 * (jj >> 2) + 4 * (lane >> 4) + (jj & 3);
        int n = b * 16 + (lane & 15);
        fr2[FR3_M2U + r] = bf16u(fw[F_U2 + i * 4096 + t * 64 + n]);
        return;
    }
}

// ---------------- counting sort: hist -> scan -> scatter ----------------
__global__ __launch_bounds__(256) void hist_kernel(const int* __restrict__ ei, int* __restrict__ cnt) {
    int e = blockIdx.x * 256 + threadIdx.x;
    if (e < N_EDGES) atomicAdd(&cnt[ei[N_EDGES + e]], 1);
}

__global__ __launch_bounds__(256) void scan1_kernel(const int* __restrict__ cnt,
                                                    int* __restrict__ off, int* __restrict__ bsum) {
    __shared__ int sh[256];
    int t = threadIdx.x, i = blockIdx.x * 256 + t;
    int v = (i < N_NODES) ? cnt[i] : 0;
    sh[t] = v; __syncthreads();
    for (int d = 1; d < 256; d <<= 1) {
        int add = (t >= d) ? sh[t - d] : 0;
        __syncthreads();
        sh[t] += add;
        __syncthreads();
    }
    if (i < N_NODES) off[i] = sh[t] - v;
    if (t == 255) bsum[blockIdx.x] = sh[255];
}

__global__ __launch_bounds__(256) void scan2_kernel(int* __restrict__ bsum) {
    __shared__ int sh[256];
    int t = threadIdx.x;
    int v = (t < 196) ? bsum[t] : 0;
    sh[t] = v; __syncthreads();
    for (int d = 1; d < 256; d <<= 1) {
        int add = (t >= d) ? sh[t - d] : 0;
        __syncthreads();
        sh[t] += add;
        __syncthreads();
    }
    bsum[t] = sh[t] - v;
}

__global__ __launch_bounds__(256) void scan3_kernel(int* __restrict__ off, const int* __restrict__ bsum,
                                                    int* __restrict__ cur) {
    int i = blockIdx.x * 256 + threadIdx.x;
    if (i < N_NODES) {
        int o = off[i] + bsum[i >> 8];
        off[i] = o;
        cur[i] = o;
    }
    if (i == 0) off[N_NODES] = N_EDGES;
}

// single packed int2 write per edge (halves scattered-line count vs two arrays)
__global__ __launch_bounds__(256) void scatter_kernel(const int* __restrict__ ei, int* __restrict__ cur,
                                                      int2* __restrict__ sedge) {
    int e = blockIdx.x * 256 + threadIdx.x;
    if (e >= N_EDGES) return;
    int d = ei[N_EDGES + e];
    int p = atomicAdd(&cur[d], 1);
    sedge[p] = make_int2(ei[e], e);
}

// ---------------- MFMA edge projection (q stored as fp8 e4m3 pairs) ----------------
template<int NT>
__global__ __launch_bounds__(256, 2) void edge_mfma_kernel(
    const float* __restrict__ edge_attr, const int2* __restrict__ sedge,
    const unsigned short* __restrict__ w1frag, const float* __restrict__ b1,
    const unsigned short* __restrict__ vfrag,  const float* __restrict__ bias2,
    unsigned short* __restrict__ qout, int nTiles)
{
    const int lane = threadIdx.x & 63;
    const int wid  = threadIdx.x >> 6;
    const int col  = lane & 15;
    const int quad = lane >> 4;

    bf16x8 w1f[4];
#pragma unroll
    for (int tt = 0; tt < 4; tt++)
        w1f[tt] = *(const bf16x8*)(w1frag + (tt * 64 + lane) * 8);
    bf16x8 vf[NT][2];
#pragma unroll
    for (int nt = 0; nt < NT; nt++)
#pragma unroll
        for (int ka = 0; ka < 2; ka++)
            vf[nt][ka] = *(const bf16x8*)(vfrag + ((nt * 2 + ka) * 64 + lane) * 8);
    float4 b1v[4];
#pragma unroll
    for (int tt = 0; tt < 4; tt++)
        b1v[tt] = *(const float4*)(b1 + tt * 16 + quad * 4);
    float b2v[NT];
#pragma unroll
    for (int nt = 0; nt < NT; nt++) b2v[nt] = bias2[nt * 16 + col];

    const int gw = blockIdx.x * 4 + wid;
    const int stride = gridDim.x * 4;
    for (int t = gw; t < nTiles; t += stride) {
        const int s = t * 16 + col;
        const int e = sedge[s].y;
        bf16x8 eaf;
        uint4 eau = make_uint4(0u, 0u, 0u, 0u);
        if (quad < 2) {
            const float4 v0 = *(const float4*)(edge_attr + (size_t)e * 16 + quad * 8);
            const float4 v1 = *(const float4*)(edge_attr + (size_t)e * 16 + quad * 8 + 4);
            eau.x = packbf2(v0.x, v0.y); eau.y = packbf2(v0.z, v0.w);
            eau.z = packbf2(v1.x, v1.y); eau.w = packbf2(v1.z, v1.w);
        }
        eaf = __builtin_bit_cast(bf16x8, eau);

        f32x4 c1[4];
#pragma unroll
        for (int tt = 0; tt < 4; tt++) {
            f32x4 ci = {b1v[tt].x, b1v[tt].y, b1v[tt].z, b1v[tt].w};
            c1[tt] = __builtin_amdgcn_mfma_f32_16x16x32_bf16(w1f[tt], eaf, ci, 0, 0, 0);
        }

        bf16x8 a2[2];
#pragma unroll
        for (int ka = 0; ka < 2; ka++) {
            uint4 au;
            au.x = packbf2(fmaxf(c1[2 * ka][0], 0.f),     fmaxf(c1[2 * ka][1], 0.f));
            au.y = packbf2(fmaxf(c1[2 * ka][2], 0.f),     fmaxf(c1[2 * ka][3], 0.f));
            au.z = packbf2(fmaxf(c1[2 * ka + 1][0], 0.f), fmaxf(c1[2 * ka + 1][1], 0.f));
            au.w = packbf2(fmaxf(c1[2 * ka + 1][2], 0.f), fmaxf(c1[2 * ka + 1][3], 0.f));
            a2[ka] = __builtin_bit_cast(bf16x8, au);
        }

        f32x4 c2[NT];
#pragma unroll
        for (int nt = 0; nt < NT; nt++) {
            f32x4 ci = {b2v[nt], b2v[nt], b2v[nt], b2v[nt]};
            ci = __builtin_amdgcn_mfma_f32_16x16x32_bf16(a2[0], vf[nt][0], ci, 0, 0, 0);
            c2[nt] = __builtin_amdgcn_mfma_f32_16x16x32_bf16(a2[1], vf[nt][1], ci, 0, 0, 0);
        }

        const size_t rowb = (size_t)t * 16 + quad * 4;
#pragma unroll
        for (int b = 0; b < NT / 2; b++) {
#pragma unroll
            for (int r = 0; r < 4; r++) {
                qout[(rowb + r) * (size_t)(NT * 8) + b * 16 + col] =
                    pkfp8(c2[2 * b][r], c2[2 * b + 1][r]);
            }
        }
    }
}

// ---------------- gather layer 1: 2-edge unrolled; writes agg1[N][96] TRUE col order ----------------
__global__ __launch_bounds__(64) void gather1_kernel(
    const float* __restrict__ x, const int* __restrict__ off, const int2* __restrict__ sedge,
    const unsigned short* __restrict__ q1, float* __restrict__ agg1)
{
    const int n = blockIdx.x, l = threadIdx.x;
    if (l >= 48) return;
    const int s0 = off[n], s1 = off[n + 1];
    const int c = l & 15;
    const int n1 = (l >> 4) * 32 + c, n2 = n1 + 16;
    float a0 = 0.f, a1 = 0.f, b0 = 0.f, b1 = 0.f;
    int s = s0;
    for (; s + 2 <= s1; s += 2) {
        const int srcA = sedge[s].x, srcB = sedge[s + 1].x;
        const unsigned short uA = q1[(size_t)s * 48 + l];
        const unsigned short uB = q1[(size_t)(s + 1) * 48 + l];
        const float xA0 = x[(size_t)srcA * 32 + c], xA1 = x[(size_t)srcA * 32 + c + 16];
        const float xB0 = x[(size_t)srcB * 32 + c], xB1 = x[(size_t)srcB * 32 + c + 16];
        const f32x2 dA = unpkfp8(uA);
        const f32x2 dB = unpkfp8(uB);
        a0 += fmaxf(xA0 + dA.x, 0.f);
        a1 += fmaxf(xA1 + dA.y, 0.f);
        b0 += fmaxf(xB0 + dB.x, 0.f);
        b1 += fmaxf(xB1 + dB.y, 0.f);
    }
    if (s < s1) {
        const int src = sedge[s].x;
        const f32x2 d = unpkfp8(q1[(size_t)s * 48 + l]);
        a0 += fmaxf(x[(size_t)src * 32 + c] + d.x, 0.f);
        a1 += fmaxf(x[(size_t)src * 32 + c + 16] + d.y, 0.f);
    }
    agg1[(size_t)n * 96 + n1] = a0 + b0;
    agg1[(size_t)n * 96 + n2] = a1 + b1;
}

// ---------------- node MLP layer 1 via MFMA (16 nodes per wave) ----------------
__global__ __launch_bounds__(256) void mlp1_mfma_kernel(
    const float* __restrict__ x, const float* __restrict__ agg1,
    const unsigned short* __restrict__ fr2, const float* __restrict__ c1_b1,
    const float* __restrict__ fw, float* __restrict__ h1)
{
    const int lane = threadIdx.x & 63, wid = threadIdx.x >> 6;
    const int tile = blockIdx.x * 4 + wid;
    if (tile >= NTILES) return;
    const int col = lane & 15, quad = lane >> 4;
    const int node = tile * 16 + col;

    const float4 xa = *(const float4*)(x + (size_t)node * 32 + quad * 8);
    const float4 xb = *(const float4*)(x + (size_t)node * 32 + quad * 8 + 4);

    f32x4 c2[4];
#pragma unroll
    for (int b = 0; b < 4; b++) {
        const float ub = fw[F_UB1 + b * 16 + col];
        c2[b] = {ub, ub, ub, ub};
    }
#pragma unroll
    for (int i = 0; i < 3; i++) {
        const float4 a0 = *(const float4*)(agg1 + (size_t)node * 96 + i * 32 + quad * 8);
        const float4 a1 = *(const float4*)(agg1 + (size_t)node * 96 + i * 32 + quad * 8 + 4);
        uint4 iu;
        iu.x = packbf2(xa.x + a0.x, xa.y + a0.y);
        iu.y = packbf2(xa.z + a0.z, xa.w + a0.w);
        iu.z = packbf2(xb.x + a1.x, xb.y + a1.y);
        iu.w = packbf2(xb.z + a1.z, xb.w + a1.w);
        const bf16x8 inf = __builtin_bit_cast(bf16x8, iu);

        f32x4 c1[4];
#pragma unroll
        for (int tt = 0; tt < 4; tt++) {
            const bf16x8 wf = *(const bf16x8*)(fr2 + FR3_M1W + ((i * 4 + tt) * 64 + lane) * 8);
            const float4 bi = *(const float4*)(c1_b1 + i * 64 + tt * 16 + quad * 4);
            f32x4 ci = {bi.x, bi.y, bi.z, bi.w};
            c1[tt] = __builtin_amdgcn_mfma_f32_16x16x32_bf16(wf, inf, ci, 0, 0, 0);
        }
        bf16x8 a2[2];
#pragma unroll
        for (int ka = 0; ka < 2; ka++) {
            uint4 au;
            au.x = packbf2(fmaxf(c1[2 * ka][0], 0.f),     fmaxf(c1[2 * ka][1], 0.f));
            au.y = packbf2(fmaxf(c1[2 * ka][2], 0.f),     fmaxf(c1[2 * ka][3], 0.f));
            au.z = packbf2(fmaxf(c1[2 * ka + 1][0], 0.f), fmaxf(c1[2 * ka + 1][1], 0.f));
            au.w = packbf2(fmaxf(c1[2 * ka + 1][2], 0.f), fmaxf(c1[2 * ka + 1][3], 0.f));
            a2[ka] = __builtin_bit_cast(bf16x8, au);
        }
#pragma unroll
        for (int b = 0; b < 4; b++)
#pragma unroll
            for (int ka = 0; ka < 2; ka++) {
                const bf16x8 uf = *(const bf16x8*)(fr2 + FR3_M1U + (((i * 4 + b) * 2 + ka) * 64 + lane) * 8);
                c2[b] = __builtin_amdgcn_mfma_f32_16x16x32_bf16(a2[ka], uf, c2[b], 0, 0, 0);
            }
    }
    const int rowb = tile * 16 + quad * 4;
#pragma unroll
    for (int b = 0; b < 4; b++)
#pragma unroll
        for (int r = 0; r < 4; r++)
            h1[(size_t)(rowb + r) * 64 + b * 16 + col] = fmaxf(c2[b][r], 0.f);
}

// ---------------- gather layer 2 (full range; 2-edge unrolled) ----------------
__global__ __launch_bounds__(64) void gather2_kernel(
    const float* __restrict__ h1, const int* __restrict__ off, const int2* __restrict__ sedge,
    const unsigned short* __restrict__ q2, float* __restrict__ agg2)
{
    const int n = blockIdx.x, l = threadIdx.x;
    const int s0 = off[n], s1 = off[n + 1];

    const int k1 = ((l >> 4) & 1) * 32 + (l & 15);
    float sa0 = 0.f, sa1 = 0.f, sb0 = 0.f, sb1 = 0.f;
    float ta0 = 0.f, ta1 = 0.f, tb0 = 0.f, tb1 = 0.f;
    int s = s0;
    for (; s + 2 <= s1; s += 2) {
        const int srcA = sedge[s].x, srcB = sedge[s + 1].x;
        const float hA0 = h1[(size_t)srcA * 64 + k1];
        const float hA1 = h1[(size_t)srcA * 64 + k1 + 16];
        const float hB0 = h1[(size_t)srcB * 64 + k1];
        const float hB1 = h1[(size_t)srcB * 64 + k1 + 16];
        const f32x2 dA = unpkfp8(q2[(size_t)s * 96 + l]);
        const f32x2 dB = unpkfp8(q2[(size_t)(s + 1) * 96 + l]);
        sa0 += fmaxf(hA0 + dA.x, 0.f);
        sa1 += fmaxf(hA1 + dA.y, 0.f);
        ta0 += fmaxf(hB0 + dB.x, 0.f);
        ta1 += fmaxf(hB1 + dB.y, 0.f);
        if (l < 32) {
            const f32x2 d2A = unpkfp8(q2[(size_t)s * 96 + 64 + l]);
            const f32x2 d2B = unpkfp8(q2[(size_t)(s + 1) * 96 + 64 + l]);
            sb0 += fmaxf(hA0 + d2A.x, 0.f);
            sb1 += fmaxf(hA1 + d2A.y, 0.f);
            tb0 += fmaxf(hB0 + d2B.x, 0.f);
            tb1 += fmaxf(hB1 + d2B.y, 0.f);
        }
    }
    if (s < s1) {
        const int src = sedge[s].x;
        const float hv0 = h1[(size_t)src * 64 + k1];
        const float hv1 = h1[(size_t)src * 64 + k1 + 16];
        const f32x2 d = unpkfp8(q2[(size_t)s * 96 + l]);
        sa0 += fmaxf(hv0 + d.x, 0.f);
        sa1 += fmaxf(hv1 + d.y, 0.f);
        if (l < 32) {
            const f32x2 d2 = unpkfp8(q2[(size_t)s * 96 + 64 + l]);
            sb0 += fmaxf(hv0 + d2.x, 0.f);
            sb1 += fmaxf(hv1 + d2.y, 0.f);
        }
    }
    sa0 += ta0; sa1 += ta1; sb0 += tb0; sb1 += tb1;
    const int C1 = 32 * (l >> 4) + (l & 15);
    const int C2 = 128 + 32 * (l >> 4) + (l & 15);
    float* row = agg2 + (size_t)n * 192;
    row[C1] = sa0; row[C1 + 16] = sa1;
    if (l < 32) { row[C2] = sb0; row[C2 + 16] = sb1; }
}

// ---------------- node MLP layer 2 via MFMA (16 nodes per wave) ----------------
__global__ __launch_bounds__(256) void mlp2_mfma_kernel(
    const float* __restrict__ h1, const float* __restrict__ agg2,
    const unsigned short* __restrict__ fr2, const float* __restrict__ c2_b1,
    const float* __restrict__ fw, float* __restrict__ h2)
{
    const int lane = threadIdx.x & 63, wid = threadIdx.x >> 6;
    const int tile = blockIdx.x * 4 + wid;
    if (tile >= NTILES) return;
    const int col = lane & 15, quad = lane >> 4;
    const int node = tile * 16 + col;

    float4 hv[4];
#pragma unroll
    for (int p = 0; p < 4; p++)
        hv[p] = *(const float4*)(h1 + (size_t)node * 64 + (p >> 1) * 32 + quad * 8 + (p & 1) * 4);

    f32x4 c2[4];
#pragma unroll
    for (int b = 0; b < 4; b++) {
        const float ub = fw[F_UB2 + b * 16 + col];
        c2[b] = {ub, ub, ub, ub};
    }
#pragma unroll
    for (int i = 0; i < 3; i++) {
        bf16x8 inf[2];
#pragma unroll
        for (int ka = 0; ka < 2; ka++) {
            const float4 a0 = *(const float4*)(agg2 + (size_t)node * 192 + i * 64 + ka * 32 + quad * 8);
            const float4 a1 = *(const float4*)(agg2 + (size_t)node * 192 + i * 64 + ka * 32 + quad * 8 + 4);
            const float4 h0 = hv[ka * 2], h1v = hv[ka * 2 + 1];
            uint4 iu;
            iu.x = packbf2(h0.x + a0.x, h0.y + a0.y);
            iu.y = packbf2(h0.z + a0.z, h0.w + a0.w);
            iu.z = packbf2(h1v.x + a1.x, h1v.y + a1.y);
            iu.w = packbf2(h1v.z + a1.z, h1v.w + a1.w);
            inf[ka] = __builtin_bit_cast(bf16x8, iu);
        }
        f32x4 c1[4];
#pragma unroll
        for (int tt = 0; tt < 4; tt++) {
            const bf16x8 wf0 = *(const bf16x8*)(fr2 + FR3_M2W + (((i * 4 + tt) * 2 + 0) * 64 + lane) * 8);
            const bf16x8 wf1 = *(const bf16x8*)(fr2 + FR3_M2W + (((i * 4 + tt) * 2 + 1) * 64 + lane) * 8);
            const float4 bi = *(const float4*)(c2_b1 + i * 64 + tt * 16 + quad * 4);
            f32x4 ci = {bi.x, bi.y, bi.z, bi.w};
            ci = __builtin_amdgcn_mfma_f32_16x16x32_bf16(wf0, inf[0], ci, 0, 0, 0);
            c1[tt] = __builtin_amdgcn_mfma_f32_16x16x32_bf16(wf1, inf[1], ci, 0, 0, 0);
        }
        bf16x8 a2[2];
#pragma unroll
        for (int ka = 0; ka < 2; ka++) {
            uint4 au;
            au.x = packbf2(fmaxf(c1[2 * ka][0], 0.f),     fmaxf(c1[2 * ka][1], 0.f));
            au.y = packbf2(fmaxf(c1[2 * ka][2], 0.f),     fmaxf(c1[2 * ka][3], 0.f));
            au.z = packbf2(fmaxf(c1[2 * ka + 1][0], 0.f), fmaxf(c1[2 * ka + 1][1], 0.f));
            au.w = packbf2(fmaxf(c1[2 * ka + 1][2], 0.f), fmaxf(c1[2 * ka + 1][3], 0.f));
            a2[ka] = __builtin_bit_cast(bf16x8, au);
        }
#pragma unroll
        for (int b = 0; b < 4; b++)
#pragma unroll
            for (int ka = 0; ka < 2; ka++) {
                const bf16x8 uf = *(const bf16x8*)(fr2 + FR3_M2U + (((i * 4 + b) * 2 + ka) * 64 + lane) * 8);
                c2[b] = __builtin_amdgcn_mfma_f32_16x16x32_bf16(a2[ka], uf, c2[b], 0, 0, 0);
            }
    }
    const int rowb = tile * 16 + quad * 4;
#pragma unroll
    for (int b = 0; b < 4; b++)
#pragma unroll
        for (int r = 0; r < 4; r++)
            h2[(size_t)(rowb + r) * 64 + b * 16 + col] = fmaxf(c2[b][r], 0.f);
}

// ---------------- pooling + head (fused; batch is sorted) ----------------
__global__ __launch_bounds__(256) void pool_kernel(
    const float* __restrict__ h2, const int* __restrict__ batch,
    const float* __restrict__ u, const float* __restrict__ fc_w,
    const float* __restrict__ fc_b, float* __restrict__ out)
{
    __shared__ float red[256];
    const int g = blockIdx.x, t = threadIdx.x;
    int lo = 0, hi = N_NODES;
    while (lo < hi) { int m = (lo + hi) >> 1; if (batch[m] < g) lo = m + 1; else hi = m; }
    int lo2 = lo, hi2 = N_NODES;
    while (lo2 < hi2) { int m = (lo2 + hi2) >> 1; if (batch[m] < g + 1) lo2 = m + 1; else hi2 = m; }

    const int col = t & 63, ch = t >> 6;
    float s = 0.f;
    for (int idx = lo + ch; idx < lo2; idx += 4) s += h2[(size_t)idx * 64 + col];
    red[t] = s;
    __syncthreads();
    if (t < 64) red[t] = red[t] + red[64 + t] + red[128 + t] + red[192 + t];
    __syncthreads();
    if (t == 0) {
        const float inv = 1.f / fmaxf((float)(lo2 - lo), 1.f);
        float sv = fc_b[0];
        for (int j = 0; j < 64; j++) sv = fmaf(red[j] * inv, fc_w[j], sv);
        for (int k = 0; k < 32; k++) sv = fmaf(u[(size_t)g * 32 + k], fc_w[64 + k], sv);
        out[g] = sv;
    }
}

extern "C" void kernel_launch(void* const* d_in, const int* in_sizes, int n_in,
                              void* d_out, int out_size, void* d_ws, size_t ws_size,
                              hipStream_t stream) {
    (void)in_sizes; (void)n_in; (void)out_size; (void)ws_size;
    const float* x        = (const float*)d_in[0];
    const float* edge_attr= (const float*)d_in[1];
    const float* u        = (const float*)d_in[2];
    const float* em1_w1   = (const float*)d_in[3];
    const float* em1_b1   = (const float*)d_in[4];
    const float* em1_w2   = (const float*)d_in[5];
    const float* em1_b2   = (const float*)d_in[6];
    const float* em2_w1   = (const float*)d_in[7];
    const float* em2_b1   = (const float*)d_in[8];
    const float* em2_w2   = (const float*)d_in[9];
    const float* em2_b2   = (const float*)d_in[10];
    const float* c1_lin_w = (const float*)d_in[11];
    const float* c1_lin_b = (const float*)d_in[12];
    const float* c1_w1    = (const float*)d_in[13];
    const float* c1_b1    = (const float*)d_in[14];
    const float* c1_w2    = (const float*)d_in[15];
    const float* c1_b2    = (const float*)d_in[16];
    const float* c2_lin_w = (const float*)d_in[17];
    const float* c2_lin_b = (const float*)d_in[18];
    const float* c2_w1    = (const float*)d_in[19];
    const float* c2_b1    = (const float*)d_in[20];
    const float* c2_w2    = (const float*)d_in[21];
    const float* c2_b2    = (const float*)d_in[22];
    const float* lin1_w   = (const float*)d_in[23];
    const float* lin1_b   = (const float*)d_in[24];
    const float* lin2_w   = (const float*)d_in[25];
    const float* lin2_b   = (const float*)d_in[26];
    const float* fc_w     = (const float*)d_in[27];
    const float* fc_b     = (const float*)d_in[28];
    const int*   ei       = (const int*)d_in[29];
    const int*   batch    = (const int*)d_in[30];

    char* wsb = (char*)d_ws;
    int*   cnt  = (int*)(wsb + B_CNT);
    int*   off  = (int*)(wsb + B_OFF);
    int*   cur  = (int*)(wsb + B_CUR);
    int*   bsum = (int*)(wsb + B_BSUM);
    int2*  sedge= (int2*)(wsb + B_SEDGE);
    float* agg2 = (float*)(wsb + B_AGG2);   // also used as agg1 [N][96]
    unsigned short* q = (unsigned short*)(wsb + B_Q);
    float* h1   = (float*)(wsb + B_H1);
    float* h2   = (float*)(wsb + B_H2);
    float* fw   = (float*)(wsb + B_FOLD);
    unsigned short* fr  = (unsigned short*)(wsb + B_FRAG);
    unsigned short* fr2 = (unsigned short*)(wsb + B_FR2);
    float* out  = (float*)d_out;

    (void)hipMemsetAsync(d_ws, 0, ZERO_BYTES, stream);   // histogram counters only

    fold_kernel<<<(FOLD_TOTAL + 255) / 256, 256, 0, stream>>>(
        em1_w2, em1_b2, em2_w2, em2_b2, c1_lin_w, c1_lin_b, c2_lin_w, c2_lin_b,
        c1_w2, c1_b2, c2_w2, c2_b2, lin1_w, lin1_b, lin2_w, lin2_b, fw);
    fold2_kernel<<<(FOLD2_TOTAL + 255) / 256, 256, 0, stream>>>(em1_w1, em2_w1, fw, fr);
    fold3_kernel<<<(FOLD3_TOTAL + 255) / 256, 256, 0, stream>>>(c1_w1, c2_w1, fw, fr2);

    // counting sort by dst
    hist_kernel<<<N_EDGES / 256, 256, 0, stream>>>(ei, cnt);
    scan1_kernel<<<196, 256, 0, stream>>>(cnt, off, bsum);
    scan2_kernel<<<1, 256, 0, stream>>>(bsum);
    scan3_kernel<<<196, 256, 0, stream>>>(off, bsum, cur);
    scatter_kernel<<<N_EDGES / 256, 256, 0, stream>>>(ei, cur, sedge);

    // layer 1
    edge_mfma_kernel<6><<<2048, 256, 0, stream>>>(
        edge_attr, sedge, fr + FR_W1E1, em1_b1, fr + FR_V1, fw + F_B1F, q, N_EDGES / 16);
    gather1_kernel<<<N_NODES, 64, 0, stream>>>(x, off, sedge, q, agg2);
    mlp1_mfma_kernel<<<(NTILES + 3) / 4, 256, 0, stream>>>(x, agg2, fr2, c1_b1, fw, h1);

    // layer 2 (single pass: fp8 q2 fits the whole edge set)
    edge_mfma_kernel<12><<<2048, 256, 0, stream>>>(
        edge_attr, sedge, fr + FR_W1E2, em2_b1, fr + FR_V2, fw + F_B2F, q, N_EDGES / 16);
    gather2_kernel<<<N_NODES, 64, 0, stream>>>(h1, off, sedge, q, agg2);
    mlp2_mfma_kernel<<<(NTILES + 3) / 4, 256, 0, stream>>>(h1, agg2, fr2, c2_b1, fw, h2);

    // pooling + head (fused)
    pool_kernel<<<N_GRAPHS, 256, 0, stream>>>(h2, batch, u, fc_w, fc_b, out);
}